// Round 1
// baseline (455.590 us; speedup 1.0000x reference)
//
#include <hip/hip_runtime.h>
#include <stdint.h>

#define SEQ 2048
#define BSZ 4
#define NH 16
#define HD 64
#define EMB 1024

using bf16x8 = __attribute__((ext_vector_type(8))) __bf16;
using u16x8  = __attribute__((ext_vector_type(8))) unsigned short;
using f32x4  = __attribute__((ext_vector_type(4))) float;

__device__ __forceinline__ unsigned short f2bf(float f) {
    union { float f; uint32_t u; } v; v.f = f;
    uint32_t r = v.u + 0x7fffu + ((v.u >> 16) & 1u);
    return (unsigned short)(r >> 16);
}

// ---------------- cast fp32 -> bf16 ----------------
__global__ void cast_kernel(const float* __restrict__ s, unsigned short* __restrict__ d, int n) {
    int i = (blockIdx.x * blockDim.x + threadIdx.x) * 4;
    if (i + 3 >= n) {
        for (int j = 0; j < 4 && i + j < n; ++j) d[i + j] = f2bf(s[i + j]);
        return;
    }
    float4 v = *(const float4*)(s + i);
    ushort4 o;
    o.x = f2bf(v.x); o.y = f2bf(v.y); o.z = f2bf(v.z); o.w = f2bf(v.w);
    *(ushort4*)(d + i) = o;
}

// ---------------- GEMM: C[M,N] = A[M,K] * Bw[N,K]^T + bias ----------------
// A, Bw bf16 row-major. OUT_BF16=1 -> ushort out, else float out.
template <int OUT_BF16>
__global__ __launch_bounds__(256, 2)
void gemm_bt(const unsigned short* __restrict__ A,
             const unsigned short* __restrict__ Bw,
             const float* __restrict__ bias,
             void* __restrict__ Cout,
             int M, int N, int Kd) {
    __shared__ unsigned short As[128][72];   // +8 pad: fragment reads 2-way only
    __shared__ unsigned short Bs[128][72];

    const int t    = threadIdx.x;
    const int lane = t & 63;
    const int wid  = t >> 6;
    const int g    = lane >> 4;
    const int lr   = lane & 15;
    const int wm   = wid >> 1, wn = wid & 1;
    const int m0   = blockIdx.x * 128, n0 = blockIdx.y * 128;

    f32x4 acc[4][4];
    const f32x4 zero = {0.f, 0.f, 0.f, 0.f};
#pragma unroll
    for (int i = 0; i < 4; ++i)
#pragma unroll
        for (int j = 0; j < 4; ++j) acc[i][j] = zero;

    for (int kt = 0; kt < Kd; kt += 64) {
#pragma unroll
        for (int p = 0; p < 4; ++p) {
            int chunk = p * 256 + t;
            int row = chunk >> 3;
            int c8  = (chunk & 7) << 3;
            *(u16x8*)&As[row][c8] = *(const u16x8*)(A  + (size_t)(m0 + row) * Kd + kt + c8);
            *(u16x8*)&Bs[row][c8] = *(const u16x8*)(Bw + (size_t)(n0 + row) * Kd + kt + c8);
        }
        __syncthreads();
#pragma unroll
        for (int ks = 0; ks < 2; ++ks) {
            bf16x8 af[4], bfr[4];
#pragma unroll
            for (int m = 0; m < 4; ++m)
                af[m] = *(const bf16x8*)&As[wm * 64 + m * 16 + lr][ks * 32 + g * 8];
#pragma unroll
            for (int n = 0; n < 4; ++n)
                bfr[n] = *(const bf16x8*)&Bs[wn * 64 + n * 16 + lr][ks * 32 + g * 8];
#pragma unroll
            for (int m = 0; m < 4; ++m)
#pragma unroll
                for (int n = 0; n < 4; ++n)
                    acc[m][n] = __builtin_amdgcn_mfma_f32_16x16x32_bf16(af[m], bfr[n], acc[m][n], 0, 0, 0);
        }
        __syncthreads();
    }

#pragma unroll
    for (int n = 0; n < 4; ++n) {
        int colg = n0 + wn * 64 + n * 16 + lr;
        float bv = bias[colg];
#pragma unroll
        for (int m = 0; m < 4; ++m) {
            int rowg = m0 + wm * 64 + m * 16 + g * 4;
#pragma unroll
            for (int r = 0; r < 4; ++r) {
                float val = acc[m][n][r] + bv;
                if (OUT_BF16)
                    ((unsigned short*)Cout)[(size_t)(rowg + r) * N + colg] = f2bf(val);
                else
                    ((float*)Cout)[(size_t)(rowg + r) * N + colg] = val;
            }
        }
    }
}

// ---------------- Flash attention ----------------
// grid: (SEQ/64, NH, BSZ); block 256 = 4 waves; wave handles 16 q-rows.
__global__ __launch_bounds__(256, 2)
void flash_attn(const unsigned short* __restrict__ Q,
                const unsigned short* __restrict__ K,
                const unsigned short* __restrict__ V,
                unsigned short* __restrict__ O) {
    __shared__ unsigned short Ks[64][72];
    __shared__ unsigned short Vt[64][72];      // transposed: Vt[d][k]
    __shared__ unsigned short Ps[4][16][72];   // per-wave P tile

    const int t    = threadIdx.x;
    const int wid  = t >> 6;
    const int lane = t & 63;
    const int g    = lane >> 4;
    const int lr   = lane & 15;
    const int b    = blockIdx.z, h = blockIdx.y;
    const int q0   = blockIdx.x * 64 + wid * 16;
    const size_t rowbase = (size_t)b * SEQ;

    // Q fragments (A-layout): lane holds Q[q0+lr][g*8 + ks*32 + j]
    bf16x8 qf[2];
#pragma unroll
    for (int ks = 0; ks < 2; ++ks)
        qf[ks] = *(const bf16x8*)(Q + (rowbase + q0 + lr) * EMB + h * HD + ks * 32 + g * 8);

    float mrow[4], lrow[4];
    f32x4 o[4];
    const f32x4 zero = {0.f, 0.f, 0.f, 0.f};
#pragma unroll
    for (int r = 0; r < 4; ++r) { mrow[r] = -3.0e38f; lrow[r] = 0.f; }
#pragma unroll
    for (int n = 0; n < 4; ++n) o[n] = zero;

    for (int kt = 0; kt < SEQ / 64; ++kt) {
        __syncthreads();   // previous tile fully consumed
#pragma unroll
        for (int p = 0; p < 2; ++p) {
            int chunk = p * 256 + t;
            int row = chunk >> 3;
            int c8  = (chunk & 7) << 3;
            *(u16x8*)&Ks[row][c8] =
                *(const u16x8*)(K + (rowbase + kt * 64 + row) * EMB + h * HD + c8);
            u16x8 vv = *(const u16x8*)(V + (rowbase + kt * 64 + row) * EMB + h * HD + c8);
#pragma unroll
            for (int j = 0; j < 8; ++j) Vt[c8 + j][row] = vv[j];
        }
        __syncthreads();

        // S = Q K^T (then *1/8)
        float sv[4][4];
#pragma unroll
        for (int kk = 0; kk < 4; ++kk) {
            f32x4 s = zero;
#pragma unroll
            for (int ks = 0; ks < 2; ++ks) {
                bf16x8 kf = *(const bf16x8*)&Ks[kk * 16 + lr][ks * 32 + g * 8];
                s = __builtin_amdgcn_mfma_f32_16x16x32_bf16(qf[ks], kf, s, 0, 0, 0);
            }
#pragma unroll
            for (int r = 0; r < 4; ++r) sv[kk][r] = s[r] * 0.125f;
        }

        // online softmax over this tile's 64 cols
        float p[4][4], alpha[4];
#pragma unroll
        for (int r = 0; r < 4; ++r) {
            float vmax = fmaxf(fmaxf(sv[0][r], sv[1][r]), fmaxf(sv[2][r], sv[3][r]));
#pragma unroll
            for (int d = 1; d < 16; d <<= 1) vmax = fmaxf(vmax, __shfl_xor(vmax, d));
            float mn = fmaxf(mrow[r], vmax);
            alpha[r] = __expf(mrow[r] - mn);
            float rs = 0.f;
#pragma unroll
            for (int kk = 0; kk < 4; ++kk) { p[kk][r] = __expf(sv[kk][r] - mn); rs += p[kk][r]; }
#pragma unroll
            for (int d = 1; d < 16; d <<= 1) rs += __shfl_xor(rs, d);
            lrow[r] = lrow[r] * alpha[r] + rs;
            mrow[r] = mn;
        }
#pragma unroll
        for (int n = 0; n < 4; ++n)
#pragma unroll
            for (int r = 0; r < 4; ++r) o[n][r] *= alpha[r];

        // P -> LDS (D-layout row = g*4+r, col = kk*16+lr), then read back as A-frag
#pragma unroll
        for (int kk = 0; kk < 4; ++kk)
#pragma unroll
            for (int r = 0; r < 4; ++r)
                Ps[wid][g * 4 + r][kk * 16 + lr] = f2bf(p[kk][r]);

#pragma unroll
        for (int ks = 0; ks < 2; ++ks) {
            bf16x8 pf = *(const bf16x8*)&Ps[wid][lr][ks * 32 + g * 8];
#pragma unroll
            for (int n = 0; n < 4; ++n) {
                bf16x8 vf = *(const bf16x8*)&Vt[n * 16 + lr][ks * 32 + g * 8];
                o[n] = __builtin_amdgcn_mfma_f32_16x16x32_bf16(pf, vf, o[n], 0, 0, 0);
            }
        }
    }

    // write O (bf16) at [b, q, h*64 + d]
#pragma unroll
    for (int n = 0; n < 4; ++n) {
        int colg = h * HD + n * 16 + lr;
#pragma unroll
        for (int r = 0; r < 4; ++r) {
            int qrow = q0 + g * 4 + r;
            O[(rowbase + qrow) * EMB + colg] = f2bf(o[n][r] / lrow[r]);
        }
    }
}

extern "C" void kernel_launch(void* const* d_in, const int* in_sizes, int n_in,
                              void* d_out, int out_size, void* d_ws, size_t ws_size,
                              hipStream_t stream) {
    const float* x  = (const float*)d_in[0];
    const float* wq = (const float*)d_in[1];
    const float* bq = (const float*)d_in[2];
    const float* wk = (const float*)d_in[3];
    const float* bk = (const float*)d_in[4];
    const float* wv = (const float*)d_in[5];
    const float* bv = (const float*)d_in[6];
    const float* wo = (const float*)d_in[7];
    const float* bo = (const float*)d_in[8];

    char* ws = (char*)d_ws;
    const size_t M = (size_t)BSZ * SEQ;              // 8192
    unsigned short* xb  = (unsigned short*)ws;                         // 16 MB, reused as attn_out
    unsigned short* wqb = (unsigned short*)(ws + (size_t)16 * 1024 * 1024);
    unsigned short* wkb = wqb + 1024 * 1024;
    unsigned short* wvb = wkb + 1024 * 1024;
    unsigned short* wob = wvb + 1024 * 1024;
    unsigned short* Qb  = (unsigned short*)(ws + (size_t)24 * 1024 * 1024);
    unsigned short* Kb  = Qb + M * EMB;
    unsigned short* Vb  = Kb + M * EMB;

    const int nX = (int)(M * EMB);
    cast_kernel<<<nX / 1024, 256, 0, stream>>>(x, xb, nX);
    cast_kernel<<<1024, 256, 0, stream>>>(wq, wqb, EMB * EMB);
    cast_kernel<<<1024, 256, 0, stream>>>(wk, wkb, EMB * EMB);
    cast_kernel<<<1024, 256, 0, stream>>>(wv, wvb, EMB * EMB);
    cast_kernel<<<1024, 256, 0, stream>>>(wo, wob, EMB * EMB);

    dim3 gg(64, 8);
    gemm_bt<1><<<gg, 256, 0, stream>>>(xb, wqb, bq, Qb, (int)M, EMB, EMB);
    gemm_bt<1><<<gg, 256, 0, stream>>>(xb, wkb, bk, Kb, (int)M, EMB, EMB);
    gemm_bt<1><<<gg, 256, 0, stream>>>(xb, wvb, bv, Vb, (int)M, EMB, EMB);

    flash_attn<<<dim3(SEQ / 64, NH, BSZ), 256, 0, stream>>>(Qb, Kb, Vb, xb);

    gemm_bt<0><<<gg, 256, 0, stream>>>(xb, wob, bo, d_out, (int)M, EMB, EMB);
}

// Round 2
// 369.246 us; speedup vs baseline: 1.2338x; 1.2338x over previous
//
#include <hip/hip_runtime.h>
#include <stdint.h>

#define SEQ 2048
#define BSZ 4
#define NH 16
#define HD 64
#define EMB 1024
#define NT (SEQ / 64)

using bf16x8 = __attribute__((ext_vector_type(8))) __bf16;
using u16x8  = __attribute__((ext_vector_type(8))) unsigned short;
using u32x4  = __attribute__((ext_vector_type(4))) uint32_t;
using f32x4  = __attribute__((ext_vector_type(4))) float;

__device__ __forceinline__ unsigned short f2bf(float f) {
    union { float f; uint32_t u; } v; v.f = f;
    uint32_t r = v.u + 0x7fffu + ((v.u >> 16) & 1u);
    return (unsigned short)(r >> 16);
}

// ---------------- cast fp32 -> bf16 ----------------
__global__ void cast_kernel(const float* __restrict__ s, unsigned short* __restrict__ d, int n) {
    int i = (blockIdx.x * blockDim.x + threadIdx.x) * 4;
    if (i + 3 >= n) {
        for (int j = 0; j < 4 && i + j < n; ++j) d[i + j] = f2bf(s[i + j]);
        return;
    }
    float4 v = *(const float4*)(s + i);
    ushort4 o;
    o.x = f2bf(v.x); o.y = f2bf(v.y); o.z = f2bf(v.z); o.w = f2bf(v.w);
    *(ushort4*)(d + i) = o;
}

// ---------------- GEMM: C[M,N] = A[M,K] * Bw[N,K]^T + bias ----------------
template <int OUT_BF16>
__global__ __launch_bounds__(256, 2)
void gemm_bt(const unsigned short* __restrict__ A,
             const unsigned short* __restrict__ Bw,
             const float* __restrict__ bias,
             void* __restrict__ Cout,
             int M, int N, int Kd) {
    __shared__ unsigned short As[128][72];
    __shared__ unsigned short Bs[128][72];

    const int t    = threadIdx.x;
    const int lane = t & 63;
    const int wid  = t >> 6;
    const int g    = lane >> 4;
    const int lr   = lane & 15;
    const int wm   = wid >> 1, wn = wid & 1;
    const int m0   = blockIdx.x * 128, n0 = blockIdx.y * 128;

    f32x4 acc[4][4];
    const f32x4 zero = {0.f, 0.f, 0.f, 0.f};
#pragma unroll
    for (int i = 0; i < 4; ++i)
#pragma unroll
        for (int j = 0; j < 4; ++j) acc[i][j] = zero;

    for (int kt = 0; kt < Kd; kt += 64) {
#pragma unroll
        for (int p = 0; p < 4; ++p) {
            int chunk = p * 256 + t;
            int row = chunk >> 3;
            int c8  = (chunk & 7) << 3;
            *(u16x8*)&As[row][c8] = *(const u16x8*)(A  + (size_t)(m0 + row) * Kd + kt + c8);
            *(u16x8*)&Bs[row][c8] = *(const u16x8*)(Bw + (size_t)(n0 + row) * Kd + kt + c8);
        }
        __syncthreads();
#pragma unroll
        for (int ks = 0; ks < 2; ++ks) {
            bf16x8 af[4], bfr[4];
#pragma unroll
            for (int m = 0; m < 4; ++m)
                af[m] = *(const bf16x8*)&As[wm * 64 + m * 16 + lr][ks * 32 + g * 8];
#pragma unroll
            for (int n = 0; n < 4; ++n)
                bfr[n] = *(const bf16x8*)&Bs[wn * 64 + n * 16 + lr][ks * 32 + g * 8];
#pragma unroll
            for (int m = 0; m < 4; ++m)
#pragma unroll
                for (int n = 0; n < 4; ++n)
                    acc[m][n] = __builtin_amdgcn_mfma_f32_16x16x32_bf16(af[m], bfr[n], acc[m][n], 0, 0, 0);
        }
        __syncthreads();
    }

#pragma unroll
    for (int n = 0; n < 4; ++n) {
        int colg = n0 + wn * 64 + n * 16 + lr;
        float bv = bias[colg];
#pragma unroll
        for (int m = 0; m < 4; ++m) {
            int rowg = m0 + wm * 64 + m * 16 + g * 4;
#pragma unroll
            for (int r = 0; r < 4; ++r) {
                float val = acc[m][n][r] + bv;
                if (OUT_BF16)
                    ((unsigned short*)Cout)[(size_t)(rowg + r) * N + colg] = f2bf(val);
                else
                    ((float*)Cout)[(size_t)(rowg + r) * N + colg] = val;
            }
        }
    }
}

// ---- 8x8 register transpose round (butterfly over lane bits 0..2) ----
// Each of 8 lanes holds u16x8 (as 4 dwords). After rounds M=4,2,1:
// new[i][j] = old[j][i].
template <int M>
__device__ __forceinline__ void xr(uint32_t d[4], int i) {
    uint32_t o[4];
#pragma unroll
    for (int k = 0; k < 4; ++k) o[k] = (uint32_t)__shfl_xor((int)d[k], M);
    if (M == 1) {
        bool hi = (i & 1) != 0;
#pragma unroll
        for (int k = 0; k < 4; ++k)
            d[k] = hi ? ((d[k] & 0xffff0000u) | (o[k] >> 16))
                      : ((d[k] & 0x0000ffffu) | (o[k] << 16));
    } else {
        const int mb = M >> 1;   // dword-block size
        bool hi = (i & M) != 0;
#pragma unroll
        for (int jd = 0; jd < 4; ++jd) {
            bool jdhi = (jd & mb) != 0;
            d[jd] = (jdhi != hi) ? o[jd ^ mb] : d[jd];
        }
    }
}

// ---------------- Flash attention v2 ----------------
// grid: (SEQ/128, NH, BSZ); block 256 = 4 waves; wave handles 2 q-tiles of 16.
__global__ __launch_bounds__(256, 2)
void flash_attn(const unsigned short* __restrict__ Q,
                const unsigned short* __restrict__ K,
                const unsigned short* __restrict__ V,
                unsigned short* __restrict__ O) {
    __shared__ unsigned short Ks[64][72];
    __shared__ unsigned short Vt[64][72];      // Vt[d][k]
    __shared__ unsigned short Ps[4][16][72];   // per-wave P tile (reused per qi)

    const int t    = threadIdx.x;
    const int wid  = t >> 6;
    const int lane = t & 63;
    const int g    = lane >> 4;
    const int lr   = lane & 15;
    const int il   = lane & 7;                 // transpose-group row
    const int b    = blockIdx.z, h = blockIdx.y;
    const int q0w  = blockIdx.x * 128 + wid * 32;
    const size_t rowbase = (size_t)b * SEQ;
    const unsigned short* Kh = K + rowbase * EMB + h * HD;
    const unsigned short* Vh = V + rowbase * EMB + h * HD;

    // Q fragments: lane holds Q[q0w+qi*16+lr][ks*32 + g*8 + j]
    bf16x8 qf[2][2];
#pragma unroll
    for (int qi = 0; qi < 2; ++qi)
#pragma unroll
        for (int ks = 0; ks < 2; ++ks)
            qf[qi][ks] = *(const bf16x8*)(Q + (rowbase + q0w + qi * 16 + lr) * EMB
                                            + h * HD + ks * 32 + g * 8);

    float mrow[2][4], lrow[2][4];
    f32x4 o[2][4];
    const f32x4 zero = {0.f, 0.f, 0.f, 0.f};
#pragma unroll
    for (int qi = 0; qi < 2; ++qi)
#pragma unroll
        for (int r = 0; r < 4; ++r) { mrow[qi][r] = -3.0e38f; lrow[qi][r] = 0.f; }
#pragma unroll
    for (int qi = 0; qi < 2; ++qi)
#pragma unroll
        for (int n = 0; n < 4; ++n) o[qi][n] = zero;

    u16x8 kreg[2], vreg[2];
    auto load_tile = [&](int kt) {
#pragma unroll
        for (int p = 0; p < 2; ++p) {
            int c = p * 256 + t;
            kreg[p] = *(const u16x8*)(Kh + (size_t)(kt * 64 + (c >> 3)) * EMB + ((c & 7) << 3));
        }
#pragma unroll
        for (int q = 0; q < 2; ++q)
            vreg[q] = *(const u16x8*)(Vh + (size_t)(kt * 64 + (q * 4 + wid) * 8 + il) * EMB
                                         + (((lane >> 3) & 7) << 3));
    };
    load_tile(0);

    for (int kt = 0; kt < NT; ++kt) {
        // in-register 8x8 transpose of the V chunk (lanes grouped by lane>>3)
        uint32_t tv[2][4];
#pragma unroll
        for (int q = 0; q < 2; ++q) {
            u32x4 w = __builtin_bit_cast(u32x4, vreg[q]);
#pragma unroll
            for (int k = 0; k < 4; ++k) tv[q][k] = w[k];
            xr<4>(tv[q], il);
            xr<2>(tv[q], il);
            xr<1>(tv[q], il);
        }

        __syncthreads();   // all waves done reading previous tile
#pragma unroll
        for (int p = 0; p < 2; ++p) {
            int c = p * 256 + t;
            *(u16x8*)&Ks[c >> 3][(c & 7) << 3] = kreg[p];
        }
        // lane (a=lane>>3, i=lane&7) holds V columns a*8+i = lane, rows (q*4+wid)*8..+7
#pragma unroll
        for (int q = 0; q < 2; ++q)
            *(u32x4*)&Vt[lane][(q * 4 + wid) * 8] = *(u32x4*)tv[q];
        __syncthreads();

        if (kt + 1 < NT) load_tile(kt + 1);   // prefetch hides under compute

        // per q-subtile: QK^T -> online softmax -> P staging -> fragment
        bf16x8 pf[2][2];
        float alpha[2][4];
#pragma unroll
        for (int qi = 0; qi < 2; ++qi) {
            float p2[4][4];
#pragma unroll
            for (int kk = 0; kk < 4; ++kk) {
                bf16x8 kf0 = *(const bf16x8*)&Ks[kk * 16 + lr][g * 8];
                bf16x8 kf1 = *(const bf16x8*)&Ks[kk * 16 + lr][32 + g * 8];
                f32x4 s = zero;
                s = __builtin_amdgcn_mfma_f32_16x16x32_bf16(qf[qi][0], kf0, s, 0, 0, 0);
                s = __builtin_amdgcn_mfma_f32_16x16x32_bf16(qf[qi][1], kf1, s, 0, 0, 0);
#pragma unroll
                for (int r = 0; r < 4; ++r) p2[kk][r] = s[r] * 0.125f;
            }
#pragma unroll
            for (int r = 0; r < 4; ++r) {
                float vmax = fmaxf(fmaxf(p2[0][r], p2[1][r]), fmaxf(p2[2][r], p2[3][r]));
#pragma unroll
                for (int d = 1; d < 16; d <<= 1) vmax = fmaxf(vmax, __shfl_xor(vmax, d));
                float mn = fmaxf(mrow[qi][r], vmax);
                alpha[qi][r] = __expf(mrow[qi][r] - mn);
                float rs = 0.f;
#pragma unroll
                for (int kk = 0; kk < 4; ++kk) { p2[kk][r] = __expf(p2[kk][r] - mn); rs += p2[kk][r]; }
#pragma unroll
                for (int d = 1; d < 16; d <<= 1) rs += __shfl_xor(rs, d);
                lrow[qi][r] = lrow[qi][r] * alpha[qi][r] + rs;
                mrow[qi][r] = mn;
            }
#pragma unroll
            for (int kk = 0; kk < 4; ++kk)
#pragma unroll
                for (int r = 0; r < 4; ++r)
                    Ps[wid][g * 4 + r][kk * 16 + lr] = f2bf(p2[kk][r]);
            pf[qi][0] = *(const bf16x8*)&Ps[wid][lr][g * 8];
            pf[qi][1] = *(const bf16x8*)&Ps[wid][lr][32 + g * 8];
        }
#pragma unroll
        for (int qi = 0; qi < 2; ++qi)
#pragma unroll
            for (int n = 0; n < 4; ++n)
#pragma unroll
                for (int r = 0; r < 4; ++r) o[qi][n][r] *= alpha[qi][r];

        // PV: vf shared across both q-subtiles
#pragma unroll
        for (int ks = 0; ks < 2; ++ks)
#pragma unroll
            for (int n = 0; n < 4; ++n) {
                bf16x8 vf = *(const bf16x8*)&Vt[n * 16 + lr][ks * 32 + g * 8];
#pragma unroll
                for (int qi = 0; qi < 2; ++qi)
                    o[qi][n] = __builtin_amdgcn_mfma_f32_16x16x32_bf16(pf[qi][ks], vf, o[qi][n], 0, 0, 0);
            }
    }

#pragma unroll
    for (int qi = 0; qi < 2; ++qi)
#pragma unroll
        for (int n = 0; n < 4; ++n) {
            int colg = h * HD + n * 16 + lr;
#pragma unroll
            for (int r = 0; r < 4; ++r) {
                int qrow = q0w + qi * 16 + g * 4 + r;
                O[(rowbase + qrow) * EMB + colg] = f2bf(o[qi][n][r] / lrow[qi][r]);
            }
        }
}

extern "C" void kernel_launch(void* const* d_in, const int* in_sizes, int n_in,
                              void* d_out, int out_size, void* d_ws, size_t ws_size,
                              hipStream_t stream) {
    const float* x  = (const float*)d_in[0];
    const float* wq = (const float*)d_in[1];
    const float* bq = (const float*)d_in[2];
    const float* wk = (const float*)d_in[3];
    const float* bk = (const float*)d_in[4];
    const float* wv = (const float*)d_in[5];
    const float* bv = (const float*)d_in[6];
    const float* wo = (const float*)d_in[7];
    const float* bo = (const float*)d_in[8];

    char* ws = (char*)d_ws;
    const size_t M = (size_t)BSZ * SEQ;              // 8192
    unsigned short* xb  = (unsigned short*)ws;                         // 16 MB, reused as attn_out
    unsigned short* wqb = (unsigned short*)(ws + (size_t)16 * 1024 * 1024);
    unsigned short* wkb = wqb + 1024 * 1024;
    unsigned short* wvb = wkb + 1024 * 1024;
    unsigned short* wob = wvb + 1024 * 1024;
    unsigned short* Qb  = (unsigned short*)(ws + (size_t)24 * 1024 * 1024);
    unsigned short* Kb  = Qb + M * EMB;
    unsigned short* Vb  = Kb + M * EMB;

    const int nX = (int)(M * EMB);
    cast_kernel<<<nX / 1024, 256, 0, stream>>>(x, xb, nX);
    cast_kernel<<<1024, 256, 0, stream>>>(wq, wqb, EMB * EMB);
    cast_kernel<<<1024, 256, 0, stream>>>(wk, wkb, EMB * EMB);
    cast_kernel<<<1024, 256, 0, stream>>>(wv, wvb, EMB * EMB);
    cast_kernel<<<1024, 256, 0, stream>>>(wo, wob, EMB * EMB);

    dim3 gg(64, 8);
    gemm_bt<1><<<gg, 256, 0, stream>>>(xb, wqb, bq, Qb, (int)M, EMB, EMB);
    gemm_bt<1><<<gg, 256, 0, stream>>>(xb, wkb, bk, Kb, (int)M, EMB, EMB);
    gemm_bt<1><<<gg, 256, 0, stream>>>(xb, wvb, bv, Vb, (int)M, EMB, EMB);

    flash_attn<<<dim3(SEQ / 128, NH, BSZ), 256, 0, stream>>>(Qb, Kb, Vb, xb);

    gemm_bt<0><<<gg, 256, 0, stream>>>(xb, wob, bo, d_out, (int)M, EMB, EMB);
}

// Round 3
// 262.226 us; speedup vs baseline: 1.7374x; 1.4081x over previous
//
#include <hip/hip_runtime.h>
#include <stdint.h>

#define SEQ 2048
#define BSZ 4
#define NH 16
#define HD 64
#define EMB 1024
#define NT (SEQ / 64)

using bf16x8 = __attribute__((ext_vector_type(8))) __bf16;
using u16x8  = __attribute__((ext_vector_type(8))) unsigned short;
using u32x4  = __attribute__((ext_vector_type(4))) uint32_t;
using f32x4  = __attribute__((ext_vector_type(4))) float;
using f32x16 = __attribute__((ext_vector_type(16))) float;

__device__ __forceinline__ unsigned short f2bf(float f) {
    union { float f; uint32_t u; } v; v.f = f;
    uint32_t r = v.u + 0x7fffu + ((v.u >> 16) & 1u);
    return (unsigned short)(r >> 16);
}

__device__ __forceinline__ uint32_t cvtpk(float lo, float hi) {
    uint32_t r;
    asm("v_cvt_pk_bf16_f32 %0, %1, %2" : "=v"(r) : "v"(lo), "v"(hi));
    return r;
}
// exchanges a.hi-lanes <-> b.lo-lanes: a' = [a.lo | b.lo], b' = [a.hi | b.hi]
__device__ __forceinline__ void plswap(uint32_t& a, uint32_t& b) {
    asm volatile("v_permlane32_swap_b32 %0, %1" : "+v"(a), "+v"(b));
}

// ---------------- cast fp32 -> bf16 ----------------
__global__ void cast_kernel(const float* __restrict__ s, unsigned short* __restrict__ d, int n) {
    int i = (blockIdx.x * blockDim.x + threadIdx.x) * 4;
    if (i + 3 >= n) {
        for (int j = 0; j < 4 && i + j < n; ++j) d[i + j] = f2bf(s[i + j]);
        return;
    }
    float4 v = *(const float4*)(s + i);
    ushort4 o;
    o.x = f2bf(v.x); o.y = f2bf(v.y); o.z = f2bf(v.z); o.w = f2bf(v.w);
    *(ushort4*)(d + i) = o;
}

// ---------------- GEMM: C[M,N] = A[M,K] * Bw[N,K]^T + bias ----------------
template <int OUT_BF16>
__global__ __launch_bounds__(256, 2)
void gemm_bt(const unsigned short* __restrict__ A,
             const unsigned short* __restrict__ Bw,
             const float* __restrict__ bias,
             void* __restrict__ Cout,
             int M, int N, int Kd) {
    __shared__ unsigned short As[128][72];
    __shared__ unsigned short Bs[128][72];

    const int t    = threadIdx.x;
    const int lane = t & 63;
    const int wid  = t >> 6;
    const int g    = lane >> 4;
    const int lr   = lane & 15;
    const int wm   = wid >> 1, wn = wid & 1;
    const int m0   = blockIdx.x * 128, n0 = blockIdx.y * 128;

    f32x4 acc[4][4];
    const f32x4 zero = {0.f, 0.f, 0.f, 0.f};
#pragma unroll
    for (int i = 0; i < 4; ++i)
#pragma unroll
        for (int j = 0; j < 4; ++j) acc[i][j] = zero;

    for (int kt = 0; kt < Kd; kt += 64) {
#pragma unroll
        for (int p = 0; p < 4; ++p) {
            int chunk = p * 256 + t;
            int row = chunk >> 3;
            int c8  = (chunk & 7) << 3;
            *(u16x8*)&As[row][c8] = *(const u16x8*)(A  + (size_t)(m0 + row) * Kd + kt + c8);
            *(u16x8*)&Bs[row][c8] = *(const u16x8*)(Bw + (size_t)(n0 + row) * Kd + kt + c8);
        }
        __syncthreads();
#pragma unroll
        for (int ks = 0; ks < 2; ++ks) {
            bf16x8 af[4], bfr[4];
#pragma unroll
            for (int m = 0; m < 4; ++m)
                af[m] = *(const bf16x8*)&As[wm * 64 + m * 16 + lr][ks * 32 + g * 8];
#pragma unroll
            for (int n = 0; n < 4; ++n)
                bfr[n] = *(const bf16x8*)&Bs[wn * 64 + n * 16 + lr][ks * 32 + g * 8];
#pragma unroll
            for (int m = 0; m < 4; ++m)
#pragma unroll
                for (int n = 0; n < 4; ++n)
                    acc[m][n] = __builtin_amdgcn_mfma_f32_16x16x32_bf16(af[m], bfr[n], acc[m][n], 0, 0, 0);
        }
        __syncthreads();
    }

#pragma unroll
    for (int n = 0; n < 4; ++n) {
        int colg = n0 + wn * 64 + n * 16 + lr;
        float bv = bias[colg];
#pragma unroll
        for (int m = 0; m < 4; ++m) {
            int rowg = m0 + wm * 64 + m * 16 + g * 4;
#pragma unroll
            for (int r = 0; r < 4; ++r) {
                float val = acc[m][n][r] + bv;
                if (OUT_BF16)
                    ((unsigned short*)Cout)[(size_t)(rowg + r) * N + colg] = f2bf(val);
                else
                    ((float*)Cout)[(size_t)(rowg + r) * N + colg] = val;
            }
        }
    }
}

// ---- 8x8 register transpose round (butterfly over lane bits 0..2) ----
template <int M>
__device__ __forceinline__ void xr(uint32_t d[4], int i) {
    uint32_t o[4];
#pragma unroll
    for (int k = 0; k < 4; ++k) o[k] = (uint32_t)__shfl_xor((int)d[k], M);
    if (M == 1) {
        bool hi = (i & 1) != 0;
#pragma unroll
        for (int k = 0; k < 4; ++k)
            d[k] = hi ? ((d[k] & 0xffff0000u) | (o[k] >> 16))
                      : ((d[k] & 0x0000ffffu) | (o[k] << 16));
    } else {
        const int mb = M >> 1;
        bool hi = (i & M) != 0;
#pragma unroll
        for (int jd = 0; jd < 4; ++jd) {
            bool jdhi = (jd & mb) != 0;
            d[jd] = (jdhi != hi) ? o[jd ^ mb] : d[jd];
        }
    }
}

// ---------------- Flash attention v3: swapped QK^T, in-register softmax ----
// grid: (SEQ/128, NH, BSZ); block 256 = 4 waves; wave handles 32 q-rows.
// 32x32x16 MFMA. S^T = mfma(K, Q): lane holds P-row for q = lane&31.
__global__ __launch_bounds__(256, 2)
void flash_attn(const unsigned short* __restrict__ Q,
                const unsigned short* __restrict__ K,
                const unsigned short* __restrict__ V,
                unsigned short* __restrict__ O) {
    __shared__ unsigned char KsB[64 * 128];   // K[k][d], XOR-16B swizzled
    __shared__ unsigned char VtB[64 * 128];   // V^T[d][k], XOR-16B swizzled

    const int t    = threadIdx.x;
    const int wid  = t >> 6;
    const int lane = t & 63;
    const int l31  = lane & 31;
    const int hi   = lane >> 5;
    const int hi16 = hi << 4;
    const int sw   = (l31 & 7) << 4;
    const int il   = lane & 7;
    const int b    = blockIdx.z, h = blockIdx.y;
    const int qbase = blockIdx.x * 128 + wid * 32;
    const size_t rowbase = (size_t)b * SEQ;
    const unsigned short* Kh = K + rowbase * EMB + h * HD;
    const unsigned short* Vh = V + rowbase * EMB + h * HD;

    // Q fragments (B-operand): lane holds Q[qbase+l31][db*16 + hi*8 + j]
    bf16x8 qf[4];
#pragma unroll
    for (int db = 0; db < 4; ++db)
        qf[db] = *(const bf16x8*)(Q + (rowbase + qbase + l31) * EMB + h * HD + db * 16 + hi * 8);

    f32x16 o0, o1;
#pragma unroll
    for (int r = 0; r < 16; ++r) { o0[r] = 0.f; o1[r] = 0.f; }
    float me = -1e30f, lsum = 0.f;

    u16x8 kreg[2], vreg[2];
    auto load_tile = [&](int kt) {
#pragma unroll
        for (int p = 0; p < 2; ++p) {
            int c = p * 256 + t;
            kreg[p] = *(const u16x8*)(Kh + (size_t)(kt * 64 + (c >> 3)) * EMB + ((c & 7) << 3));
        }
#pragma unroll
        for (int vq = 0; vq < 2; ++vq)
            vreg[vq] = *(const u16x8*)(Vh + (size_t)(kt * 64 + (vq * 4 + wid) * 8 + il) * EMB
                                          + (((lane >> 3) & 7) << 3));
    };
    load_tile(0);

    for (int kt = 0; kt < NT; ++kt) {
        // in-register 8x8 transpose of the V chunk
        uint32_t tv[2][4];
#pragma unroll
        for (int vq = 0; vq < 2; ++vq) {
            u32x4 w = __builtin_bit_cast(u32x4, vreg[vq]);
#pragma unroll
            for (int k = 0; k < 4; ++k) tv[vq][k] = w[k];
            xr<4>(tv[vq], il);
            xr<2>(tv[vq], il);
            xr<1>(tv[vq], il);
        }

        __syncthreads();
#pragma unroll
        for (int p = 0; p < 2; ++p) {
            int c = p * 256 + t;
            int row = c >> 3;
            *(u16x8*)(KsB + row * 128 + ((((c & 7) << 4)) ^ ((row & 7) << 4))) = kreg[p];
        }
        // lane holds V column d = lane, rows (vq*4+wid)*8..+7
#pragma unroll
        for (int vq = 0; vq < 2; ++vq)
            *(u32x4*)(VtB + lane * 128 + ((((vq * 4 + wid) << 4)) ^ ((lane & 7) << 4))) = *(u32x4*)tv[vq];
        __syncthreads();

        if (kt + 1 < NT) load_tile(kt + 1);

        // S^T = K * Q^T : s0 = k-rows 0-31, s1 = k-rows 32-63; col = q = lane&31
        f32x16 s0, s1;
#pragma unroll
        for (int r = 0; r < 16; ++r) { s0[r] = 0.f; s1[r] = 0.f; }
#pragma unroll
        for (int db = 0; db < 4; ++db) {
            bf16x8 kf0 = *(const bf16x8*)(KsB + l31 * 128        + ((db * 32 + hi16) ^ sw));
            bf16x8 kf1 = *(const bf16x8*)(KsB + (l31 + 32) * 128 + ((db * 32 + hi16) ^ sw));
            s0 = __builtin_amdgcn_mfma_f32_32x32x16_bf16(kf0, qf[db], s0, 0, 0, 0);
            s1 = __builtin_amdgcn_mfma_f32_32x32x16_bf16(kf1, qf[db], s1, 0, 0, 0);
        }

        // row max (this lane holds 32 of 64 k-values for its q; partner has rest)
        float pm = s0[0];
#pragma unroll
        for (int r = 1; r < 16; ++r) pm = fmaxf(pm, s0[r]);
#pragma unroll
        for (int r = 0; r < 16; ++r) pm = fmaxf(pm, s1[r]);
        pm = fmaxf(pm, __shfl_xor(pm, 32));
        float pl = pm * 0.125f;

        // defer-max: only rescale when max grew by > 8
        if (!__all(pl - me <= 8.0f)) {
            float mn = fmaxf(me, pl);
            float al = __expf(me - mn);
            me = mn;
            lsum *= al;
#pragma unroll
            for (int r = 0; r < 16; ++r) {
                int addr = hi16 + (((r & 3) + 8 * (r >> 2)) << 2);
                float ar = __int_as_float(
                    __builtin_amdgcn_ds_bpermute(addr, __float_as_int(al)));
                o0[r] *= ar; o1[r] *= ar;
            }
        }

        // exp + row sum (in place)
        float rs = 0.f;
#pragma unroll
        for (int r = 0; r < 16; ++r) { s0[r] = __expf(fmaf(s0[r], 0.125f, -me)); rs += s0[r]; }
#pragma unroll
        for (int r = 0; r < 16; ++r) { s1[r] = __expf(fmaf(s1[r], 0.125f, -me)); rs += s1[r]; }
        rs += __shfl_xor(rs, 32);
        lsum += rs;

        // pack P -> bf16 A-fragments via cvt_pk + permlane32_swap
        bf16x8 pa[4];
#pragma unroll
        for (int kb = 0; kb < 2; ++kb) {
            uint32_t dw[8];
#pragma unroll
            for (int i = 0; i < 8; ++i)
                dw[i] = kb == 0 ? cvtpk(s0[2 * i], s0[2 * i + 1])
                                : cvtpk(s1[2 * i], s1[2 * i + 1]);
            plswap(dw[0], dw[2]); plswap(dw[1], dw[3]);
            plswap(dw[4], dw[6]); plswap(dw[5], dw[7]);
            u32x4 w0 = {dw[0], dw[1], dw[2], dw[3]};
            u32x4 w1 = {dw[4], dw[5], dw[6], dw[7]};
            pa[kb * 2]     = __builtin_bit_cast(bf16x8, w0);
            pa[kb * 2 + 1] = __builtin_bit_cast(bf16x8, w1);
        }

        // PV: o[db] += P * V  (V fragments from transposed, swizzled LDS)
#pragma unroll
        for (int kk = 0; kk < 4; ++kk) {
            bf16x8 vf0 = *(const bf16x8*)(VtB + l31 * 128        + ((kk * 32 + hi16) ^ sw));
            bf16x8 vf1 = *(const bf16x8*)(VtB + (l31 + 32) * 128 + ((kk * 32 + hi16) ^ sw));
            o0 = __builtin_amdgcn_mfma_f32_32x32x16_bf16(pa[kk], vf0, o0, 0, 0, 0);
            o1 = __builtin_amdgcn_mfma_f32_32x32x16_bf16(pa[kk], vf1, o1, 0, 0, 0);
        }
    }

    // epilogue: divide by l (redistribute lane-indexed l to reg-layout), store bf16
#pragma unroll
    for (int r = 0; r < 16; ++r) {
        int addr = hi16 + (((r & 3) + 8 * (r >> 2)) << 2);
        float lr_ = __int_as_float(__builtin_amdgcn_ds_bpermute(addr, __float_as_int(lsum)));
        float inv = 1.0f / lr_;
        int q = qbase + (r & 3) + 8 * (r >> 2) + 4 * hi;
        size_t ro = (rowbase + q) * EMB + h * HD;
        O[ro + l31]      = f2bf(o0[r] * inv);
        O[ro + 32 + l31] = f2bf(o1[r] * inv);
    }
}

extern "C" void kernel_launch(void* const* d_in, const int* in_sizes, int n_in,
                              void* d_out, int out_size, void* d_ws, size_t ws_size,
                              hipStream_t stream) {
    const float* x  = (const float*)d_in[0];
    const float* wq = (const float*)d_in[1];
    const float* bq = (const float*)d_in[2];
    const float* wk = (const float*)d_in[3];
    const float* bk = (const float*)d_in[4];
    const float* wv = (const float*)d_in[5];
    const float* bv = (const float*)d_in[6];
    const float* wo = (const float*)d_in[7];
    const float* bo = (const float*)d_in[8];

    char* ws = (char*)d_ws;
    const size_t M = (size_t)BSZ * SEQ;              // 8192
    unsigned short* xb  = (unsigned short*)ws;                         // 16 MB, reused as attn_out
    unsigned short* wqb = (unsigned short*)(ws + (size_t)16 * 1024 * 1024);
    unsigned short* wkb = wqb + 1024 * 1024;
    unsigned short* wvb = wkb + 1024 * 1024;
    unsigned short* wob = wvb + 1024 * 1024;
    unsigned short* Qb  = (unsigned short*)(ws + (size_t)24 * 1024 * 1024);
    unsigned short* Kb  = Qb + M * EMB;
    unsigned short* Vb  = Kb + M * EMB;

    const int nX = (int)(M * EMB);
    cast_kernel<<<nX / 1024, 256, 0, stream>>>(x, xb, nX);
    cast_kernel<<<1024, 256, 0, stream>>>(wq, wqb, EMB * EMB);
    cast_kernel<<<1024, 256, 0, stream>>>(wk, wkb, EMB * EMB);
    cast_kernel<<<1024, 256, 0, stream>>>(wv, wvb, EMB * EMB);
    cast_kernel<<<1024, 256, 0, stream>>>(wo, wob, EMB * EMB);

    dim3 gg(64, 8);
    gemm_bt<1><<<gg, 256, 0, stream>>>(xb, wqb, bq, Qb, (int)M, EMB, EMB);
    gemm_bt<1><<<gg, 256, 0, stream>>>(xb, wkb, bk, Kb, (int)M, EMB, EMB);
    gemm_bt<1><<<gg, 256, 0, stream>>>(xb, wvb, bv, Vb, (int)M, EMB, EMB);

    flash_attn<<<dim3(SEQ / 128, NH, BSZ), 256, 0, stream>>>(Qb, Kb, Vb, xb);

    gemm_bt<0><<<gg, 256, 0, stream>>>(xb, wob, bo, d_out, (int)M, EMB, EMB);
}

// Round 5
// 237.202 us; speedup vs baseline: 1.9207x; 1.1055x over previous
//
#include <hip/hip_runtime.h>
#include <stdint.h>

#define SEQ 2048
#define BSZ 4
#define NH 16
#define HD 64
#define EMB 1024
#define NT (SEQ / 64)
#define QSCALE 0.1803368801111f   // 0.125 * log2(e)

using bf16x8 = __attribute__((ext_vector_type(8))) __bf16;
using u16x8  = __attribute__((ext_vector_type(8))) unsigned short;
using u32x4  = __attribute__((ext_vector_type(4))) uint32_t;
using f32x4  = __attribute__((ext_vector_type(4))) float;
using f32x16 = __attribute__((ext_vector_type(16))) float;

__device__ __forceinline__ float exp2v(float x) { return __builtin_amdgcn_exp2f(x); }

__device__ __forceinline__ unsigned short f2bf(float f) {
    union { float f; uint32_t u; } v; v.f = f;
    uint32_t r = v.u + 0x7fffu + ((v.u >> 16) & 1u);
    return (unsigned short)(r >> 16);
}

__device__ __forceinline__ uint32_t cvtpk(float lo, float hi) {
    uint32_t r;
    asm("v_cvt_pk_bf16_f32 %0, %1, %2" : "=v"(r) : "v"(lo), "v"(hi));
    return r;
}
__device__ __forceinline__ void plswap(uint32_t& a, uint32_t& b) {
    asm volatile("v_permlane32_swap_b32 %0, %1" : "+v"(a), "+v"(b));
}

// async global->LDS, 16B per lane; dest = wave-uniform base + lane*16
__device__ __forceinline__ void gload16(void* lds, const void* g) {
    __builtin_amdgcn_global_load_lds(
        (const __attribute__((address_space(1))) void*)g,
        (__attribute__((address_space(3))) void*)lds, 16, 0, 0);
}

// ---------------- cast fp32 -> bf16 ----------------
__global__ void cast_kernel(const float* __restrict__ s, unsigned short* __restrict__ d, int n) {
    int i = (blockIdx.x * blockDim.x + threadIdx.x) * 4;
    if (i + 3 >= n) {
        for (int j = 0; j < 4 && i + j < n; ++j) d[i + j] = f2bf(s[i + j]);
        return;
    }
    float4 v = *(const float4*)(s + i);
    ushort4 o;
    o.x = f2bf(v.x); o.y = f2bf(v.y); o.z = f2bf(v.z); o.w = f2bf(v.w);
    *(ushort4*)(d + i) = o;
}

// ---------------- GEMM (m97 structure): C = A[M,K] * Bw[N,K]^T + bias ------
// MODE 0: f32 out to C0 (bias b0).  MODE 2: QKV fused — by 0-7 -> Q (scaled
// by QSCALE), 8-15 -> K, 16-23 -> V; bf16 outs, each [M][1024].
template <int MODE>
__global__ __launch_bounds__(256, 2)
void gemm_bt(const unsigned short* __restrict__ A,
             const unsigned short* __restrict__ Bw,
             const float* __restrict__ b0, const float* __restrict__ b1,
             const float* __restrict__ b2,
             void* __restrict__ C0, void* __restrict__ C1, void* __restrict__ C2,
             int M, int N, int Kd) {
    __shared__ unsigned short As[128][64];
    __shared__ unsigned short Bs[128][64];

    const int t    = threadIdx.x;
    const int lane = t & 63;
    const int wid  = t >> 6;
    const int g    = lane >> 4;
    const int lr   = lane & 15;
    const int wm   = wid >> 1, wn = wid & 1;
    const int m0   = blockIdx.x * 128, n0 = blockIdx.y * 128;
    const int srow = lane >> 3;          // 0..7 within 8-row stripe
    const int scol = (lane & 7) * 8;     // shorts

    f32x4 acc[4][4];
    const f32x4 zero = {0.f, 0.f, 0.f, 0.f};
#pragma unroll
    for (int i = 0; i < 4; ++i)
#pragma unroll
        for (int j = 0; j < 4; ++j) acc[i][j] = zero;

    for (int kt = 0; kt < Kd; kt += 64) {
#pragma unroll
        for (int p = 0; p < 4; ++p) {
            int rowA = wid * 32 + p * 8;
            gload16(&As[rowA][0], A  + (size_t)(m0 + rowA + srow) * Kd + kt + scol);
            gload16(&Bs[rowA][0], Bw + (size_t)(n0 + rowA + srow) * Kd + kt + scol);
        }
        __syncthreads();   // compiler drains vmcnt before barrier
#pragma unroll
        for (int ks = 0; ks < 2; ++ks) {
            bf16x8 af[4], bfr[4];
#pragma unroll
            for (int m = 0; m < 4; ++m)
                af[m] = *(const bf16x8*)&As[wm * 64 + m * 16 + lr][ks * 32 + g * 8];
#pragma unroll
            for (int n = 0; n < 4; ++n)
                bfr[n] = *(const bf16x8*)&Bs[wn * 64 + n * 16 + lr][ks * 32 + g * 8];
#pragma unroll
            for (int m = 0; m < 4; ++m)
#pragma unroll
                for (int n = 0; n < 4; ++n)
                    acc[m][n] = __builtin_amdgcn_mfma_f32_16x16x32_bf16(af[m], bfr[n], acc[m][n], 0, 0, 0);
        }
        __syncthreads();
    }

    const float* bias;
    unsigned short* Cw = nullptr;
    float* Cf = nullptr;
    float scl = 1.0f;
    int nl;
    if (MODE == 2) {
        int seg = n0 >> 10;
        bias = seg == 0 ? b0 : (seg == 1 ? b1 : b2);
        Cw = (unsigned short*)(seg == 0 ? C0 : (seg == 1 ? C1 : C2));
        scl = seg == 0 ? QSCALE : 1.0f;
        nl = n0 & 1023;
    } else {
        bias = b0; Cf = (float*)C0; nl = n0;
    }
#pragma unroll
    for (int n = 0; n < 4; ++n) {
        int colL = nl + wn * 64 + n * 16 + lr;
        float bv = bias[colL];
#pragma unroll
        for (int m = 0; m < 4; ++m) {
            int rowg = m0 + wm * 64 + m * 16 + g * 4;
#pragma unroll
            for (int r = 0; r < 4; ++r) {
                float val = (acc[m][n][r] + bv) * scl;
                if (MODE == 2)
                    Cw[(size_t)(rowg + r) * EMB + colL] = f2bf(val);
                else
                    Cf[(size_t)(rowg + r) * EMB + colL] = val;
            }
        }
    }
}

// ---- 8x8 register transpose round (butterfly over lane bits 0..2) ----
template <int M>
__device__ __forceinline__ void xr(uint32_t d[4], int i) {
    uint32_t o[4];
#pragma unroll
    for (int k = 0; k < 4; ++k) o[k] = (uint32_t)__shfl_xor((int)d[k], M);
    if (M == 1) {
        bool hi = (i & 1) != 0;
#pragma unroll
        for (int k = 0; k < 4; ++k)
            d[k] = hi ? ((d[k] & 0xffff0000u) | (o[k] >> 16))
                      : ((d[k] & 0x0000ffffu) | (o[k] << 16));
    } else {
        const int mb = M >> 1;
        bool hi = (i & M) != 0;
#pragma unroll
        for (int jd = 0; jd < 4; ++jd) {
            bool jdhi = (jd & mb) != 0;
            d[jd] = (jdhi != hi) ? o[jd ^ mb] : d[jd];
        }
    }
}

// ---------------- Flash attention v4: dbuf LDS, exp2, setprio --------------
// Q pre-scaled by 0.125*log2e -> scores are base-2 logits.
__global__ __launch_bounds__(256, 2)
void flash_attn(const unsigned short* __restrict__ Q,
                const unsigned short* __restrict__ K,
                const unsigned short* __restrict__ V,
                unsigned short* __restrict__ O) {
    __shared__ unsigned char KsB[2][64 * 128];   // K[k][d], XOR-16B swizzled
    __shared__ unsigned char VtB[2][64 * 128];   // V^T[d][k], XOR-16B swizzled

    const int t    = threadIdx.x;
    const int wid  = t >> 6;
    const int lane = t & 63;
    const int l31  = lane & 31;
    const int hi   = lane >> 5;
    const int hi16 = hi << 4;
    const int sw   = (l31 & 7) << 4;
    const int il   = lane & 7;
    const int b    = blockIdx.z, h = blockIdx.y;
    const int qbase = blockIdx.x * 128 + wid * 32;
    const size_t rowbase = (size_t)b * SEQ;
    const unsigned short* Kh = K + rowbase * EMB + h * HD;
    const unsigned short* Vh = V + rowbase * EMB + h * HD;

    bf16x8 qf[4];
#pragma unroll
    for (int db = 0; db < 4; ++db)
        qf[db] = *(const bf16x8*)(Q + (rowbase + qbase + l31) * EMB + h * HD + db * 16 + hi * 8);

    f32x16 o0, o1;
#pragma unroll
    for (int r = 0; r < 16; ++r) { o0[r] = 0.f; o1[r] = 0.f; }
    float me = -1e30f, lsum = 0.f;

    u16x8 kreg[2], vreg[2];
    auto load_tile = [&](int kt) {
#pragma unroll
        for (int p = 0; p < 2; ++p) {
            int c = p * 256 + t;
            kreg[p] = *(const u16x8*)(Kh + (size_t)(kt * 64 + (c >> 3)) * EMB + ((c & 7) << 3));
        }
#pragma unroll
        for (int vq = 0; vq < 2; ++vq)
            vreg[vq] = *(const u16x8*)(Vh + (size_t)(kt * 64 + (vq * 4 + wid) * 8 + il) * EMB
                                          + (((lane >> 3) & 7) << 3));
    };
    load_tile(0);

    for (int kt = 0; kt < NT; ++kt) {
        unsigned char* Ks = KsB[kt & 1];
        unsigned char* Vt = VtB[kt & 1];

        // in-register 8x8 transpose of the V chunk
        uint32_t tv[2][4];
#pragma unroll
        for (int vq = 0; vq < 2; ++vq) {
            u32x4 w = __builtin_bit_cast(u32x4, vreg[vq]);
#pragma unroll
            for (int k = 0; k < 4; ++k) tv[vq][k] = w[k];
            xr<4>(tv[vq], il);
            xr<2>(tv[vq], il);
            xr<1>(tv[vq], il);
        }
        // stage tile kt into buffer kt&1 (reads of this buffer from iter kt-2
        // are separated from these writes by the barrier in iter kt-1)
#pragma unroll
        for (int p = 0; p < 2; ++p) {
            int c = p * 256 + t;
            int row = c >> 3;
            *(u16x8*)(Ks + row * 128 + ((((c & 7) << 4)) ^ ((row & 7) << 4))) = kreg[p];
        }
#pragma unroll
        for (int vq = 0; vq < 2; ++vq)
            *(u32x4*)(Vt + lane * 128 + ((((vq * 4 + wid) << 4)) ^ ((lane & 7) << 4))) = *(u32x4*)tv[vq];

        if (kt + 1 < NT) load_tile(kt + 1);   // prefetch next tile into regs

        __syncthreads();                      // writes visible; prev reads done

        // S^T = K * Q^T : lane holds 32 k-scores for q = lane&31 (base-2 logits)
        f32x16 s0, s1;
#pragma unroll
        for (int r = 0; r < 16; ++r) { s0[r] = 0.f; s1[r] = 0.f; }
        __builtin_amdgcn_s_setprio(1);
#pragma unroll
        for (int db = 0; db < 4; ++db) {
            bf16x8 kf0 = *(const bf16x8*)(Ks + l31 * 128        + ((db * 32 + hi16) ^ sw));
            bf16x8 kf1 = *(const bf16x8*)(Ks + (l31 + 32) * 128 + ((db * 32 + hi16) ^ sw));
            s0 = __builtin_amdgcn_mfma_f32_32x32x16_bf16(kf0, qf[db], s0, 0, 0, 0);
            s1 = __builtin_amdgcn_mfma_f32_32x32x16_bf16(kf1, qf[db], s1, 0, 0, 0);
        }
        __builtin_amdgcn_s_setprio(0);

        // row max
        float pm = fmaxf(s0[0], s0[1]);
#pragma unroll
        for (int r = 2; r < 16; ++r) pm = fmaxf(pm, s0[r]);
#pragma unroll
        for (int r = 0; r < 16; ++r) pm = fmaxf(pm, s1[r]);
        pm = fmaxf(pm, __shfl_xor(pm, 32));

        // defer-max: only rescale when max grew by > 8 (P bounded by 2^8)
        if (!__all(pm - me <= 8.0f)) {
            float mn = fmaxf(me, pm);
            float al = exp2v(me - mn);
            me = mn;
            lsum *= al;
#pragma unroll
            for (int r = 0; r < 16; ++r) {
                int addr = hi16 + (((r & 3) + 8 * (r >> 2)) << 2);
                float ar = __int_as_float(
                    __builtin_amdgcn_ds_bpermute(addr, __float_as_int(al)));
                o0[r] *= ar; o1[r] *= ar;
            }
        }

        // exp2 + row sum (in place)
        float rs = 0.f;
#pragma unroll
        for (int r = 0; r < 16; ++r) { s0[r] = exp2v(s0[r] - me); rs += s0[r]; }
#pragma unroll
        for (int r = 0; r < 16; ++r) { s1[r] = exp2v(s1[r] - me); rs += s1[r]; }
        rs += __shfl_xor(rs, 32);
        lsum += rs;

        // pack P -> bf16 A-fragments via cvt_pk + permlane32_swap
        bf16x8 pa[4];
#pragma unroll
        for (int kb = 0; kb < 2; ++kb) {
            uint32_t dw[8];
#pragma unroll
            for (int i = 0; i < 8; ++i)
                dw[i] = kb == 0 ? cvtpk(s0[2 * i], s0[2 * i + 1])
                                : cvtpk(s1[2 * i], s1[2 * i + 1]);
            plswap(dw[0], dw[2]); plswap(dw[1], dw[3]);
            plswap(dw[4], dw[6]); plswap(dw[5], dw[7]);
            u32x4 w0 = {dw[0], dw[1], dw[2], dw[3]};
            u32x4 w1 = {dw[4], dw[5], dw[6], dw[7]};
            pa[kb * 2]     = __builtin_bit_cast(bf16x8, w0);
            pa[kb * 2 + 1] = __builtin_bit_cast(bf16x8, w1);
        }

        // PV
        __builtin_amdgcn_s_setprio(1);
#pragma unroll
        for (int kk = 0; kk < 4; ++kk) {
            bf16x8 vf0 = *(const bf16x8*)(Vt + l31 * 128        + ((kk * 32 + hi16) ^ sw));
            bf16x8 vf1 = *(const bf16x8*)(Vt + (l31 + 32) * 128 + ((kk * 32 + hi16) ^ sw));
            o0 = __builtin_amdgcn_mfma_f32_32x32x16_bf16(pa[kk], vf0, o0, 0, 0, 0);
            o1 = __builtin_amdgcn_mfma_f32_32x32x16_bf16(pa[kk], vf1, o1, 0, 0, 0);
        }
        __builtin_amdgcn_s_setprio(0);
    }

    // epilogue
#pragma unroll
    for (int r = 0; r < 16; ++r) {
        int addr = hi16 + (((r & 3) + 8 * (r >> 2)) << 2);
        float lr_ = __int_as_float(__builtin_amdgcn_ds_bpermute(addr, __float_as_int(lsum)));
        float inv = 1.0f / lr_;
        int q = qbase + (r & 3) + 8 * (r >> 2) + 4 * hi;
        size_t ro = (rowbase + q) * EMB + h * HD;
        O[ro + l31]      = f2bf(o0[r] * inv);
        O[ro + 32 + l31] = f2bf(o1[r] * inv);
    }
}

extern "C" void kernel_launch(void* const* d_in, const int* in_sizes, int n_in,
                              void* d_out, int out_size, void* d_ws, size_t ws_size,
                              hipStream_t stream) {
    const float* x  = (const float*)d_in[0];
    const float* wq = (const float*)d_in[1];
    const float* bq = (const float*)d_in[2];
    const float* wk = (const float*)d_in[3];
    const float* bk = (const float*)d_in[4];
    const float* wv = (const float*)d_in[5];
    const float* bv = (const float*)d_in[6];
    const float* wo = (const float*)d_in[7];
    const float* bo = (const float*)d_in[8];

    char* ws = (char*)d_ws;
    const size_t M = (size_t)BSZ * SEQ;              // 8192
    unsigned short* xb    = (unsigned short*)ws;                       // 16 MB, reused as attn out
    unsigned short* wqkvb = (unsigned short*)(ws + (size_t)16 * 1024 * 1024);  // 6 MB
    unsigned short* wob   = (unsigned short*)(ws + (size_t)22 * 1024 * 1024);  // 2 MB
    unsigned short* Qb    = (unsigned short*)(ws + (size_t)24 * 1024 * 1024);
    unsigned short* Kb    = Qb + M * EMB;
    unsigned short* Vb    = Kb + M * EMB;

    const int nX = (int)(M * EMB);
    cast_kernel<<<nX / 1024, 256, 0, stream>>>(x, xb, nX);
    cast_kernel<<<1024, 256, 0, stream>>>(wq, wqkvb,                 EMB * EMB);
    cast_kernel<<<1024, 256, 0, stream>>>(wk, wqkvb + 1024 * 1024,   EMB * EMB);
    cast_kernel<<<1024, 256, 0, stream>>>(wv, wqkvb + 2 * 1024 * 1024, EMB * EMB);
    cast_kernel<<<1024, 256, 0, stream>>>(wo, wob, EMB * EMB);

    gemm_bt<2><<<dim3(64, 24), 256, 0, stream>>>(xb, wqkvb, bq, bk, bv,
                                                 Qb, Kb, Vb, (int)M, 3 * EMB, EMB);

    flash_attn<<<dim3(SEQ / 128, NH, BSZ), 256, 0, stream>>>(Qb, Kb, Vb, xb);

    gemm_bt<0><<<dim3(64, 8), 256, 0, stream>>>(xb, wob, bo, nullptr, nullptr,
                                                d_out, nullptr, nullptr, (int)M, EMB, EMB);
}

// Round 6
// 221.400 us; speedup vs baseline: 2.0578x; 1.0714x over previous
//
#include <hip/hip_runtime.h>
#include <stdint.h>

#define SEQ 2048
#define BSZ 4
#define NH 16
#define HD 64
#define EMB 1024
#define NT (SEQ / 64)
#define QSCALE 0.1803368801111f   // 0.125 * log2(e)

using bf16x8 = __attribute__((ext_vector_type(8))) __bf16;
using u16x8  = __attribute__((ext_vector_type(8))) unsigned short;
using u32x4  = __attribute__((ext_vector_type(4))) uint32_t;
using f32x4  = __attribute__((ext_vector_type(4))) float;
using f32x16 = __attribute__((ext_vector_type(16))) float;

__device__ __forceinline__ float exp2v(float x) { return __builtin_amdgcn_exp2f(x); }

__device__ __forceinline__ unsigned short f2bf(float f) {
    union { float f; uint32_t u; } v; v.f = f;
    uint32_t r = v.u + 0x7fffu + ((v.u >> 16) & 1u);
    return (unsigned short)(r >> 16);
}

__device__ __forceinline__ uint32_t cvtpk(float lo, float hi) {
    uint32_t r;
    asm("v_cvt_pk_bf16_f32 %0, %1, %2" : "=v"(r) : "v"(lo), "v"(hi));
    return r;
}
__device__ __forceinline__ void plswap(uint32_t& a, uint32_t& b) {
    asm volatile("v_permlane32_swap_b32 %0, %1" : "+v"(a), "+v"(b));
}

// async global->LDS, 16B per lane; dest = wave-uniform base + lane*16
__device__ __forceinline__ void gload16(void* lds, const void* g) {
    __builtin_amdgcn_global_load_lds(
        (const __attribute__((address_space(1))) void*)g,
        (__attribute__((address_space(3))) void*)lds, 16, 0, 0);
}

// ---------------- cast fp32 -> bf16 ----------------
__global__ void cast_kernel(const float* __restrict__ s, unsigned short* __restrict__ d, int n) {
    int i = (blockIdx.x * blockDim.x + threadIdx.x) * 4;
    if (i + 3 >= n) {
        for (int j = 0; j < 4 && i + j < n; ++j) d[i + j] = f2bf(s[i + j]);
        return;
    }
    float4 v = *(const float4*)(s + i);
    ushort4 o;
    o.x = f2bf(v.x); o.y = f2bf(v.y); o.z = f2bf(v.z); o.w = f2bf(v.w);
    *(ushort4*)(d + i) = o;
}

// ---------------- GEMM (m97 structure): C = A[M,K] * Bw[N,K]^T + bias ------
// MODE 0: f32 out to C0 (bias b0).  MODE 2: QKV fused — by 0-7 -> Q (scaled
// by QSCALE), 8-15 -> K, 16-23 -> V; bf16 outs, each [M][1024].
template <int MODE>
__global__ __launch_bounds__(256, 2)
void gemm_bt(const unsigned short* __restrict__ A,
             const unsigned short* __restrict__ Bw,
             const float* __restrict__ b0, const float* __restrict__ b1,
             const float* __restrict__ b2,
             void* __restrict__ C0, void* __restrict__ C1, void* __restrict__ C2,
             int M, int N, int Kd) {
    __shared__ unsigned short As[128][64];
    __shared__ unsigned short Bs[128][64];

    const int t    = threadIdx.x;
    const int lane = t & 63;
    const int wid  = t >> 6;
    const int g    = lane >> 4;
    const int lr   = lane & 15;
    const int wm   = wid >> 1, wn = wid & 1;
    const int m0   = blockIdx.x * 128, n0 = blockIdx.y * 128;
    const int srow = lane >> 3;          // 0..7 within 8-row stripe
    const int scol = (lane & 7) * 8;     // shorts

    f32x4 acc[4][4];
    const f32x4 zero = {0.f, 0.f, 0.f, 0.f};
#pragma unroll
    for (int i = 0; i < 4; ++i)
#pragma unroll
        for (int j = 0; j < 4; ++j) acc[i][j] = zero;

    for (int kt = 0; kt < Kd; kt += 64) {
#pragma unroll
        for (int p = 0; p < 4; ++p) {
            int rowA = wid * 32 + p * 8;
            gload16(&As[rowA][0], A  + (size_t)(m0 + rowA + srow) * Kd + kt + scol);
            gload16(&Bs[rowA][0], Bw + (size_t)(n0 + rowA + srow) * Kd + kt + scol);
        }
        __syncthreads();   // compiler drains vmcnt before barrier
#pragma unroll
        for (int ks = 0; ks < 2; ++ks) {
            bf16x8 af[4], bfr[4];
#pragma unroll
            for (int m = 0; m < 4; ++m)
                af[m] = *(const bf16x8*)&As[wm * 64 + m * 16 + lr][ks * 32 + g * 8];
#pragma unroll
            for (int n = 0; n < 4; ++n)
                bfr[n] = *(const bf16x8*)&Bs[wn * 64 + n * 16 + lr][ks * 32 + g * 8];
#pragma unroll
            for (int m = 0; m < 4; ++m)
#pragma unroll
                for (int n = 0; n < 4; ++n)
                    acc[m][n] = __builtin_amdgcn_mfma_f32_16x16x32_bf16(af[m], bfr[n], acc[m][n], 0, 0, 0);
        }
        __syncthreads();
    }

    const float* bias;
    unsigned short* Cw = nullptr;
    float* Cf = nullptr;
    float scl = 1.0f;
    int nl;
    if (MODE == 2) {
        int seg = n0 >> 10;
        bias = seg == 0 ? b0 : (seg == 1 ? b1 : b2);
        Cw = (unsigned short*)(seg == 0 ? C0 : (seg == 1 ? C1 : C2));
        scl = seg == 0 ? QSCALE : 1.0f;
        nl = n0 & 1023;
    } else {
        bias = b0; Cf = (float*)C0; nl = n0;
    }
#pragma unroll
    for (int n = 0; n < 4; ++n) {
        int colL = nl + wn * 64 + n * 16 + lr;
        float bv = bias[colL];
#pragma unroll
        for (int m = 0; m < 4; ++m) {
            int rowg = m0 + wm * 64 + m * 16 + g * 4;
#pragma unroll
            for (int r = 0; r < 4; ++r) {
                float val = (acc[m][n][r] + bv) * scl;
                if (MODE == 2)
                    Cw[(size_t)(rowg + r) * EMB + colL] = f2bf(val);
                else
                    Cf[(size_t)(rowg + r) * EMB + colL] = val;
            }
        }
    }
}

// ---- 8x8 register transpose round (butterfly over lane bits 0..2) ----
template <int M>
__device__ __forceinline__ void xr(uint32_t d[4], int i) {
    uint32_t o[4];
#pragma unroll
    for (int k = 0; k < 4; ++k) o[k] = (uint32_t)__shfl_xor((int)d[k], M);
    if (M == 1) {
        bool hi = (i & 1) != 0;
#pragma unroll
        for (int k = 0; k < 4; ++k)
            d[k] = hi ? ((d[k] & 0xffff0000u) | (o[k] >> 16))
                      : ((d[k] & 0x0000ffffu) | (o[k] << 16));
    } else {
        const int mb = M >> 1;
        bool hi = (i & M) != 0;
#pragma unroll
        for (int jd = 0; jd < 4; ++jd) {
            bool jdhi = (jd & mb) != 0;
            d[jd] = (jdhi != hi) ? o[jd ^ mb] : d[jd];
        }
    }
}

// ---------------- Flash attention v5: 8-wave blocks, dbuf LDS, exp2 --------
// Q pre-scaled by 0.125*log2e -> scores are base-2 logits.
// grid: (SEQ/256, NH, BSZ) pre-swizzle; block 512 = 8 waves; wave = 32 q-rows.
__global__ __launch_bounds__(512, 4)
void flash_attn(const unsigned short* __restrict__ Q,
                const unsigned short* __restrict__ K,
                const unsigned short* __restrict__ V,
                unsigned short* __restrict__ O) {
    __shared__ unsigned char KsB[2][64 * 128];   // K[k][d], XOR-16B swizzled
    __shared__ unsigned char VtB[2][64 * 128];   // V^T[d][k], XOR-16B swizzled

    // bijective XCD swizzle: 512 blocks, 8 XCDs, 64 consecutive per XCD
    const int nwg  = gridDim.x * gridDim.y * gridDim.z;
    const int cpx  = nwg >> 3;
    const int bid0 = (blockIdx.z * gridDim.y + blockIdx.y) * gridDim.x + blockIdx.x;
    const int bid  = (bid0 % 8) * cpx + (bid0 / 8);
    const int bx   = bid & (gridDim.x - 1);          // SEQ/256 = 8 (pow2)
    const int h    = (bid >> 3) & 15;
    const int b    = bid >> 7;

    const int t    = threadIdx.x;
    const int wid  = t >> 6;
    const int lane = t & 63;
    const int l31  = lane & 31;
    const int hi   = lane >> 5;
    const int hi16 = hi << 4;
    const int sw   = (l31 & 7) << 4;
    const int il   = lane & 7;
    const int qbase = bx * 256 + wid * 32;
    const size_t rowbase = (size_t)b * SEQ;
    const unsigned short* Kh = K + rowbase * EMB + h * HD;
    const unsigned short* Vh = V + rowbase * EMB + h * HD;

    bf16x8 qf[4];
#pragma unroll
    for (int db = 0; db < 4; ++db)
        qf[db] = *(const bf16x8*)(Q + (rowbase + qbase + l31) * EMB + h * HD + db * 16 + hi * 8);

    f32x16 o0, o1;
#pragma unroll
    for (int r = 0; r < 16; ++r) { o0[r] = 0.f; o1[r] = 0.f; }
    float me = -1e30f, lsum = 0.f;

    // staging (512 threads): K row t>>3, cols (t&7)*8; V 8x8 block
    // (row-block wid, col-block lane>>3), row-in-block il.
    const int krow = t >> 3;
    const int kcol = (t & 7) << 3;
    const int vcb  = (lane >> 3) << 3;
    u16x8 kreg, vreg;
    auto load_tile = [&](int kt) {
        kreg = *(const u16x8*)(Kh + (size_t)(kt * 64 + krow) * EMB + kcol);
        vreg = *(const u16x8*)(Vh + (size_t)(kt * 64 + wid * 8 + il) * EMB + vcb);
    };
    load_tile(0);

    for (int kt = 0; kt < NT; ++kt) {
        unsigned char* Ks = KsB[kt & 1];
        unsigned char* Vt = VtB[kt & 1];

        // in-register 8x8 transpose of the V chunk (within il-group)
        uint32_t tv[4];
        {
            u32x4 w = __builtin_bit_cast(u32x4, vreg);
#pragma unroll
            for (int k = 0; k < 4; ++k) tv[k] = w[k];
            xr<4>(tv, il);
            xr<2>(tv, il);
            xr<1>(tv, il);
        }
        // stage tile kt into buffer kt&1 (reads of this buffer from iter kt-2
        // are separated from these writes by the barrier in iter kt-1)
        *(u16x8*)(Ks + krow * 128 + (((t & 7) << 4) ^ ((krow & 7) << 4))) = kreg;
        // lane holds V column vcb+il = lane, rows wid*8..+7 -> Vt[lane], slot wid
        *(u32x4*)(Vt + lane * 128 + ((wid << 4) ^ ((lane & 7) << 4))) = *(u32x4*)tv;

        if (kt + 1 < NT) load_tile(kt + 1);   // prefetch next tile into regs

        __syncthreads();                      // writes visible; prev reads done

        // S^T = K * Q^T : lane holds 32 k-scores for q = lane&31 (base-2 logits)
        f32x16 s0, s1;
#pragma unroll
        for (int r = 0; r < 16; ++r) { s0[r] = 0.f; s1[r] = 0.f; }
        __builtin_amdgcn_s_setprio(1);
#pragma unroll
        for (int db = 0; db < 4; ++db) {
            bf16x8 kf0 = *(const bf16x8*)(Ks + l31 * 128        + ((db * 32 + hi16) ^ sw));
            bf16x8 kf1 = *(const bf16x8*)(Ks + (l31 + 32) * 128 + ((db * 32 + hi16) ^ sw));
            s0 = __builtin_amdgcn_mfma_f32_32x32x16_bf16(kf0, qf[db], s0, 0, 0, 0);
            s1 = __builtin_amdgcn_mfma_f32_32x32x16_bf16(kf1, qf[db], s1, 0, 0, 0);
        }
        __builtin_amdgcn_s_setprio(0);

        // row max
        float pm = fmaxf(s0[0], s0[1]);
#pragma unroll
        for (int r = 2; r < 16; ++r) pm = fmaxf(pm, s0[r]);
#pragma unroll
        for (int r = 0; r < 16; ++r) pm = fmaxf(pm, s1[r]);
        pm = fmaxf(pm, __shfl_xor(pm, 32));

        // defer-max: only rescale when max grew by > 8 (P bounded by 2^8)
        if (!__all(pm - me <= 8.0f)) {
            float mn = fmaxf(me, pm);
            float al = exp2v(me - mn);
            me = mn;
            lsum *= al;
#pragma unroll
            for (int r = 0; r < 16; ++r) {
                int addr = hi16 + (((r & 3) + 8 * (r >> 2)) << 2);
                float ar = __int_as_float(
                    __builtin_amdgcn_ds_bpermute(addr, __float_as_int(al)));
                o0[r] *= ar; o1[r] *= ar;
            }
        }

        // exp2 + row sum (in place)
        float rs = 0.f;
#pragma unroll
        for (int r = 0; r < 16; ++r) { s0[r] = exp2v(s0[r] - me); rs += s0[r]; }
#pragma unroll
        for (int r = 0; r < 16; ++r) { s1[r] = exp2v(s1[r] - me); rs += s1[r]; }
        rs += __shfl_xor(rs, 32);
        lsum += rs;

        // pack P -> bf16 A-fragments via cvt_pk + permlane32_swap
        bf16x8 pa[4];
#pragma unroll
        for (int kb = 0; kb < 2; ++kb) {
            uint32_t dw[8];
#pragma unroll
            for (int i = 0; i < 8; ++i)
                dw[i] = kb == 0 ? cvtpk(s0[2 * i], s0[2 * i + 1])
                                : cvtpk(s1[2 * i], s1[2 * i + 1]);
            plswap(dw[0], dw[2]); plswap(dw[1], dw[3]);
            plswap(dw[4], dw[6]); plswap(dw[5], dw[7]);
            u32x4 w0 = {dw[0], dw[1], dw[2], dw[3]};
            u32x4 w1 = {dw[4], dw[5], dw[6], dw[7]};
            pa[kb * 2]     = __builtin_bit_cast(bf16x8, w0);
            pa[kb * 2 + 1] = __builtin_bit_cast(bf16x8, w1);
        }

        // PV
        __builtin_amdgcn_s_setprio(1);
#pragma unroll
        for (int kk = 0; kk < 4; ++kk) {
            bf16x8 vf0 = *(const bf16x8*)(Vt + l31 * 128        + ((kk * 32 + hi16) ^ sw));
            bf16x8 vf1 = *(const bf16x8*)(Vt + (l31 + 32) * 128 + ((kk * 32 + hi16) ^ sw));
            o0 = __builtin_amdgcn_mfma_f32_32x32x16_bf16(pa[kk], vf0, o0, 0, 0, 0);
            o1 = __builtin_amdgcn_mfma_f32_32x32x16_bf16(pa[kk], vf1, o1, 0, 0, 0);
        }
        __builtin_amdgcn_s_setprio(0);
    }

    // epilogue
#pragma unroll
    for (int r = 0; r < 16; ++r) {
        int addr = hi16 + (((r & 3) + 8 * (r >> 2)) << 2);
        float lr_ = __int_as_float(__builtin_amdgcn_ds_bpermute(addr, __float_as_int(lsum)));
        float inv = 1.0f / lr_;
        int q = qbase + (r & 3) + 8 * (r >> 2) + 4 * hi;
        size_t ro = (rowbase + q) * EMB + h * HD;
        O[ro + l31]      = f2bf(o0[r] * inv);
        O[ro + 32 + l31] = f2bf(o1[r] * inv);
    }
}

extern "C" void kernel_launch(void* const* d_in, const int* in_sizes, int n_in,
                              void* d_out, int out_size, void* d_ws, size_t ws_size,
                              hipStream_t stream) {
    const float* x  = (const float*)d_in[0];
    const float* wq = (const float*)d_in[1];
    const float* bq = (const float*)d_in[2];
    const float* wk = (const float*)d_in[3];
    const float* bk = (const float*)d_in[4];
    const float* wv = (const float*)d_in[5];
    const float* bv = (const float*)d_in[6];
    const float* wo = (const float*)d_in[7];
    const float* bo = (const float*)d_in[8];

    char* ws = (char*)d_ws;
    const size_t M = (size_t)BSZ * SEQ;              // 8192
    unsigned short* xb    = (unsigned short*)ws;                       // 16 MB, reused as attn out
    unsigned short* wqkvb = (unsigned short*)(ws + (size_t)16 * 1024 * 1024);  // 6 MB
    unsigned short* wob   = (unsigned short*)(ws + (size_t)22 * 1024 * 1024);  // 2 MB
    unsigned short* Qb    = (unsigned short*)(ws + (size_t)24 * 1024 * 1024);
    unsigned short* Kb    = Qb + M * EMB;
    unsigned short* Vb    = Kb + M * EMB;

    const int nX = (int)(M * EMB);
    cast_kernel<<<nX / 1024, 256, 0, stream>>>(x, xb, nX);
    cast_kernel<<<1024, 256, 0, stream>>>(wq, wqkvb,                 EMB * EMB);
    cast_kernel<<<1024, 256, 0, stream>>>(wk, wqkvb + 1024 * 1024,   EMB * EMB);
    cast_kernel<<<1024, 256, 0, stream>>>(wv, wqkvb + 2 * 1024 * 1024, EMB * EMB);
    cast_kernel<<<1024, 256, 0, stream>>>(wo, wob, EMB * EMB);

    gemm_bt<2><<<dim3(64, 24), 256, 0, stream>>>(xb, wqkvb, bq, bk, bv,
                                                 Qb, Kb, Vb, (int)M, 3 * EMB, EMB);

    flash_attn<<<dim3(SEQ / 256, NH, BSZ), 512, 0, stream>>>(Qb, Kb, Vb, xb);

    gemm_bt<0><<<dim3(64, 8), 256, 0, stream>>>(xb, wob, bo, nullptr, nullptr,
                                                d_out, nullptr, nullptr, (int)M, EMB, EMB);
}

// Round 7
// 204.782 us; speedup vs baseline: 2.2248x; 1.0811x over previous
//
#include <hip/hip_runtime.h>
#include <stdint.h>

#define SEQ 2048
#define BSZ 4
#define NH 16
#define HD 64
#define EMB 1024
#define NT (SEQ / 64)
#define QSCALE 0.1803368801111f   // 0.125 * log2(e)

using bf16x8 = __attribute__((ext_vector_type(8))) __bf16;
using u16x8  = __attribute__((ext_vector_type(8))) unsigned short;
using u32x4  = __attribute__((ext_vector_type(4))) uint32_t;
using f32x4  = __attribute__((ext_vector_type(4))) float;
using f32x16 = __attribute__((ext_vector_type(16))) float;

__device__ __forceinline__ float exp2v(float x) { return __builtin_amdgcn_exp2f(x); }

__device__ __forceinline__ unsigned short f2bf(float f) {
    union { float f; uint32_t u; } v; v.f = f;
    uint32_t r = v.u + 0x7fffu + ((v.u >> 16) & 1u);
    return (unsigned short)(r >> 16);
}

__device__ __forceinline__ uint32_t cvtpk(float lo, float hi) {
    uint32_t r;
    asm("v_cvt_pk_bf16_f32 %0, %1, %2" : "=v"(r) : "v"(lo), "v"(hi));
    return r;
}
__device__ __forceinline__ void plswap(uint32_t& a, uint32_t& b) {
    asm volatile("v_permlane32_swap_b32 %0, %1" : "+v"(a), "+v"(b));
}

// async global->LDS, 16B per lane; dest = wave-uniform base + lane*16
__device__ __forceinline__ void gload16(void* lds, const void* g) {
    __builtin_amdgcn_global_load_lds(
        (const __attribute__((address_space(1))) void*)g,
        (__attribute__((address_space(3))) void*)lds, 16, 0, 0);
}

// ---------------- cast fp32 -> bf16 ----------------
__global__ void cast_kernel(const float* __restrict__ s, unsigned short* __restrict__ d, int n) {
    int i = (blockIdx.x * blockDim.x + threadIdx.x) * 4;
    if (i + 3 >= n) {
        for (int j = 0; j < 4 && i + j < n; ++j) d[i + j] = f2bf(s[i + j]);
        return;
    }
    float4 v = *(const float4*)(s + i);
    ushort4 o;
    o.x = f2bf(v.x); o.y = f2bf(v.y); o.z = f2bf(v.z); o.w = f2bf(v.w);
    *(ushort4*)(d + i) = o;
}

// ---------------- GEMM (m97 structure): C = A[M,K] * Bw[N,K]^T + bias ------
// MODE 0: f32 out to C0 (bias b0).  MODE 2: QKV fused — by 0-7 -> Q (scaled
// by QSCALE), 8-15 -> K, 16-23 -> V^T (transposed write [b,h,d,seq]).
template <int MODE>
__global__ __launch_bounds__(256, 2)
void gemm_bt(const unsigned short* __restrict__ A,
             const unsigned short* __restrict__ Bw,
             const float* __restrict__ b0, const float* __restrict__ b1,
             const float* __restrict__ b2,
             void* __restrict__ C0, void* __restrict__ C1, void* __restrict__ C2,
             int M, int N, int Kd) {
    __shared__ unsigned short As[128][64];
    __shared__ unsigned short Bs[128][64];

    const int t    = threadIdx.x;
    const int lane = t & 63;
    const int wid  = t >> 6;
    const int g    = lane >> 4;
    const int lr   = lane & 15;
    const int wm   = wid >> 1, wn = wid & 1;
    const int m0   = blockIdx.x * 128, n0 = blockIdx.y * 128;
    const int srow = lane >> 3;          // 0..7 within 8-row stripe
    const int scol = (lane & 7) * 8;     // shorts

    f32x4 acc[4][4];
    const f32x4 zero = {0.f, 0.f, 0.f, 0.f};
#pragma unroll
    for (int i = 0; i < 4; ++i)
#pragma unroll
        for (int j = 0; j < 4; ++j) acc[i][j] = zero;

    for (int kt = 0; kt < Kd; kt += 64) {
#pragma unroll
        for (int p = 0; p < 4; ++p) {
            int rowA = wid * 32 + p * 8;
            gload16(&As[rowA][0], A  + (size_t)(m0 + rowA + srow) * Kd + kt + scol);
            gload16(&Bs[rowA][0], Bw + (size_t)(n0 + rowA + srow) * Kd + kt + scol);
        }
        __syncthreads();   // compiler drains vmcnt before barrier
#pragma unroll
        for (int ks = 0; ks < 2; ++ks) {
            bf16x8 af[4], bfr[4];
#pragma unroll
            for (int m = 0; m < 4; ++m)
                af[m] = *(const bf16x8*)&As[wm * 64 + m * 16 + lr][ks * 32 + g * 8];
#pragma unroll
            for (int n = 0; n < 4; ++n)
                bfr[n] = *(const bf16x8*)&Bs[wn * 64 + n * 16 + lr][ks * 32 + g * 8];
#pragma unroll
            for (int m = 0; m < 4; ++m)
#pragma unroll
                for (int n = 0; n < 4; ++n)
                    acc[m][n] = __builtin_amdgcn_mfma_f32_16x16x32_bf16(af[m], bfr[n], acc[m][n], 0, 0, 0);
        }
        __syncthreads();
    }

    int seg = MODE == 2 ? (n0 >> 10) : 0;
    if (MODE == 2 && seg == 2) {
        // V^T write: [b*1024 + colL][seq], 4 consecutive seq per ushort4
        unsigned short* CwT = (unsigned short*)C2;
        int nl = n0 & 1023;
#pragma unroll
        for (int n = 0; n < 4; ++n) {
            int colL = nl + wn * 64 + n * 16 + lr;
            float bv = b2[colL];
#pragma unroll
            for (int m = 0; m < 4; ++m) {
                int rowg = m0 + wm * 64 + m * 16 + g * 4;
                int bb = rowg >> 11, seq = rowg & 2047;
                ushort4 w;
                w.x = f2bf(acc[m][n][0] + bv);
                w.y = f2bf(acc[m][n][1] + bv);
                w.z = f2bf(acc[m][n][2] + bv);
                w.w = f2bf(acc[m][n][3] + bv);
                *(ushort4*)(CwT + ((size_t)(bb * 1024 + colL)) * SEQ + seq) = w;
            }
        }
        return;
    }

    const float* bias;
    unsigned short* Cw = nullptr;
    float* Cf = nullptr;
    float scl = 1.0f;
    int nl;
    if (MODE == 2) {
        bias = seg == 0 ? b0 : b1;
        Cw = (unsigned short*)(seg == 0 ? C0 : C1);
        scl = seg == 0 ? QSCALE : 1.0f;
        nl = n0 & 1023;
    } else {
        bias = b0; Cf = (float*)C0; nl = n0;
    }
#pragma unroll
    for (int n = 0; n < 4; ++n) {
        int colL = nl + wn * 64 + n * 16 + lr;
        float bv = bias[colL];
#pragma unroll
        for (int m = 0; m < 4; ++m) {
            int rowg = m0 + wm * 64 + m * 16 + g * 4;
#pragma unroll
            for (int r = 0; r < 4; ++r) {
                float val = (acc[m][n][r] + bv) * scl;
                if (MODE == 2)
                    Cw[(size_t)(rowg + r) * EMB + colL] = f2bf(val);
                else
                    Cf[(size_t)(rowg + r) * EMB + colL] = val;
            }
        }
    }
}

// ---------------- Flash attention v6: gload_lds staging, 8 waves -----------
// Q pre-scaled by 0.125*log2e -> scores are base-2 logits. V comes in as V^T.
// grid: 512 blocks (XCD-swizzled); block 512 = 8 waves; wave = 32 q-rows.
__global__ __launch_bounds__(512, 4)
void flash_attn(const unsigned short* __restrict__ Q,
                const unsigned short* __restrict__ K,
                const unsigned short* __restrict__ VT,
                unsigned short* __restrict__ O) {
    __shared__ unsigned char KsB[2][64 * 128];   // K[k][d],  XOR-16B swizzled
    __shared__ unsigned char VtB[2][64 * 128];   // V^T[d][k], XOR-16B swizzled

    // bijective XCD swizzle: 512 blocks, 8 XCDs, 64 consecutive per XCD
    const int nwg  = gridDim.x * gridDim.y * gridDim.z;
    const int cpx  = nwg >> 3;
    const int bid0 = (blockIdx.z * gridDim.y + blockIdx.y) * gridDim.x + blockIdx.x;
    const int bid  = (bid0 % 8) * cpx + (bid0 / 8);
    const int bx   = bid & (gridDim.x - 1);          // SEQ/256 = 8 (pow2)
    const int h    = (bid >> 3) & 15;
    const int b    = bid >> 7;

    const int t    = threadIdx.x;
    const int wid  = t >> 6;
    const int lane = t & 63;
    const int l31  = lane & 31;
    const int hi   = lane >> 5;
    const int hi16 = hi << 4;
    const int sw   = (l31 & 7) << 4;
    const int qbase = bx * 256 + wid * 32;
    const size_t rowbase = (size_t)b * SEQ;
    const unsigned short* Kh  = K + rowbase * EMB + h * HD;
    const unsigned short* Vth = VT + (size_t)(b * 1024 + h * HD) * SEQ;

    // staging geometry: slot t stages 16B; LDS linear, source pre-swizzled
    const int grow = t >> 3;                         // K row / V^T d-row
    const int gc16 = (t & 7) ^ (grow & 7);           // XOR moved to source
    const unsigned short* Ksrc0 = Kh  + (size_t)grow * EMB + gc16 * 8;
    const unsigned short* Vsrc0 = Vth + (size_t)grow * SEQ + gc16 * 8;

    bf16x8 qf[4];
#pragma unroll
    for (int db = 0; db < 4; ++db)
        qf[db] = *(const bf16x8*)(Q + (rowbase + qbase + l31) * EMB + h * HD + db * 16 + hi * 8);

    f32x16 o0, o1;
#pragma unroll
    for (int r = 0; r < 16; ++r) { o0[r] = 0.f; o1[r] = 0.f; }
    float me = -1e30f, lsum = 0.f;

    auto issue_tile = [&](int kt) {
        unsigned char* Ks = KsB[kt & 1] + wid * 1024;   // wave-uniform base
        unsigned char* Vt = VtB[kt & 1] + wid * 1024;
        gload16(Ks, Ksrc0 + (size_t)kt * 64 * EMB);     // K rows advance by kt*64
        gload16(Vt, Vsrc0 + kt * 64);                   // V^T cols advance by kt*64
    };
    issue_tile(0);

    for (int kt = 0; kt < NT; ++kt) {
        unsigned char* Ks = KsB[kt & 1];
        unsigned char* Vt = VtB[kt & 1];

        __syncthreads();                      // drains DMA for tile kt; prev reads done

        if (kt + 1 < NT) issue_tile(kt + 1);  // DMA next tile into other buffer

        // S^T = K * Q^T : lane holds 32 k-scores for q = lane&31 (base-2 logits)
        f32x16 s0, s1;
#pragma unroll
        for (int r = 0; r < 16; ++r) { s0[r] = 0.f; s1[r] = 0.f; }
        __builtin_amdgcn_s_setprio(1);
#pragma unroll
        for (int db = 0; db < 4; ++db) {
            bf16x8 kf0 = *(const bf16x8*)(Ks + l31 * 128        + ((db * 32 + hi16) ^ sw));
            bf16x8 kf1 = *(const bf16x8*)(Ks + (l31 + 32) * 128 + ((db * 32 + hi16) ^ sw));
            s0 = __builtin_amdgcn_mfma_f32_32x32x16_bf16(kf0, qf[db], s0, 0, 0, 0);
            s1 = __builtin_amdgcn_mfma_f32_32x32x16_bf16(kf1, qf[db], s1, 0, 0, 0);
        }
        __builtin_amdgcn_s_setprio(0);

        // row max (max3-friendly nesting)
        float pm = fmaxf(fmaxf(s0[0], s0[1]), s0[2]);
#pragma unroll
        for (int r = 3; r < 15; r += 2) pm = fmaxf(fmaxf(pm, s0[r]), s0[r + 1]);
        pm = fmaxf(pm, s0[15]);
#pragma unroll
        for (int r = 0; r < 16; r += 2) pm = fmaxf(fmaxf(pm, s1[r]), s1[r + 1]);
        pm = fmaxf(pm, __shfl_xor(pm, 32));

        // defer-max: only rescale when max grew by > 8 (P bounded by 2^8)
        if (!__all(pm - me <= 8.0f)) {
            float mn = fmaxf(me, pm);
            float al = exp2v(me - mn);
            me = mn;
            lsum *= al;
#pragma unroll
            for (int r = 0; r < 16; ++r) {
                int addr = hi16 + (((r & 3) + 8 * (r >> 2)) << 2);
                float ar = __int_as_float(
                    __builtin_amdgcn_ds_bpermute(addr, __float_as_int(al)));
                o0[r] *= ar; o1[r] *= ar;
            }
        }

        // exp2 + row sum (in place)
        float rs = 0.f;
#pragma unroll
        for (int r = 0; r < 16; ++r) { s0[r] = exp2v(s0[r] - me); rs += s0[r]; }
#pragma unroll
        for (int r = 0; r < 16; ++r) { s1[r] = exp2v(s1[r] - me); rs += s1[r]; }
        rs += __shfl_xor(rs, 32);
        lsum += rs;

        // pack P -> bf16 A-fragments via cvt_pk + permlane32_swap
        bf16x8 pa[4];
#pragma unroll
        for (int kb = 0; kb < 2; ++kb) {
            uint32_t dw[8];
#pragma unroll
            for (int i = 0; i < 8; ++i)
                dw[i] = kb == 0 ? cvtpk(s0[2 * i], s0[2 * i + 1])
                                : cvtpk(s1[2 * i], s1[2 * i + 1]);
            plswap(dw[0], dw[2]); plswap(dw[1], dw[3]);
            plswap(dw[4], dw[6]); plswap(dw[5], dw[7]);
            u32x4 w0 = {dw[0], dw[1], dw[2], dw[3]};
            u32x4 w1 = {dw[4], dw[5], dw[6], dw[7]};
            pa[kb * 2]     = __builtin_bit_cast(bf16x8, w0);
            pa[kb * 2 + 1] = __builtin_bit_cast(bf16x8, w1);
        }

        // PV
        __builtin_amdgcn_s_setprio(1);
#pragma unroll
        for (int kk = 0; kk < 4; ++kk) {
            bf16x8 vf0 = *(const bf16x8*)(Vt + l31 * 128        + ((kk * 32 + hi16) ^ sw));
            bf16x8 vf1 = *(const bf16x8*)(Vt + (l31 + 32) * 128 + ((kk * 32 + hi16) ^ sw));
            o0 = __builtin_amdgcn_mfma_f32_32x32x16_bf16(pa[kk], vf0, o0, 0, 0, 0);
            o1 = __builtin_amdgcn_mfma_f32_32x32x16_bf16(pa[kk], vf1, o1, 0, 0, 0);
        }
        __builtin_amdgcn_s_setprio(0);
    }

    // epilogue
#pragma unroll
    for (int r = 0; r < 16; ++r) {
        int addr = hi16 + (((r & 3) + 8 * (r >> 2)) << 2);
        float lr_ = __int_as_float(__builtin_amdgcn_ds_bpermute(addr, __float_as_int(lsum)));
        float inv = 1.0f / lr_;
        int q = qbase + (r & 3) + 8 * (r >> 2) + 4 * hi;
        size_t ro = (rowbase + q) * EMB + h * HD;
        O[ro + l31]      = f2bf(o0[r] * inv);
        O[ro + 32 + l31] = f2bf(o1[r] * inv);
    }
}

extern "C" void kernel_launch(void* const* d_in, const int* in_sizes, int n_in,
                              void* d_out, int out_size, void* d_ws, size_t ws_size,
                              hipStream_t stream) {
    const float* x  = (const float*)d_in[0];
    const float* wq = (const float*)d_in[1];
    const float* bq = (const float*)d_in[2];
    const float* wk = (const float*)d_in[3];
    const float* bk = (const float*)d_in[4];
    const float* wv = (const float*)d_in[5];
    const float* bv = (const float*)d_in[6];
    const float* wo = (const float*)d_in[7];
    const float* bo = (const float*)d_in[8];

    char* ws = (char*)d_ws;
    const size_t M = (size_t)BSZ * SEQ;              // 8192
    unsigned short* xb    = (unsigned short*)ws;                       // 16 MB, reused as attn out
    unsigned short* wqkvb = (unsigned short*)(ws + (size_t)16 * 1024 * 1024);  // 6 MB
    unsigned short* wob   = (unsigned short*)(ws + (size_t)22 * 1024 * 1024);  // 2 MB
    unsigned short* Qb    = (unsigned short*)(ws + (size_t)24 * 1024 * 1024);
    unsigned short* Kb    = Qb + M * EMB;
    unsigned short* VTb   = Kb + M * EMB;            // V^T [b*16+h][64][2048]

    const int nX = (int)(M * EMB);
    cast_kernel<<<nX / 1024, 256, 0, stream>>>(x, xb, nX);
    cast_kernel<<<1024, 256, 0, stream>>>(wq, wqkvb,                 EMB * EMB);
    cast_kernel<<<1024, 256, 0, stream>>>(wk, wqkvb + 1024 * 1024,   EMB * EMB);
    cast_kernel<<<1024, 256, 0, stream>>>(wv, wqkvb + 2 * 1024 * 1024, EMB * EMB);
    cast_kernel<<<1024, 256, 0, stream>>>(wo, wob, EMB * EMB);

    gemm_bt<2><<<dim3(64, 24), 256, 0, stream>>>(xb, wqkvb, bq, bk, bv,
                                                 Qb, Kb, VTb, (int)M, 3 * EMB, EMB);

    flash_attn<<<dim3(SEQ / 256, NH, BSZ), 512, 0, stream>>>(Qb, Kb, VTb, xb);

    gemm_bt<0><<<dim3(64, 8), 256, 0, stream>>>(xb, wob, bo, nullptr, nullptr,
                                                d_out, nullptr, nullptr, (int)M, EMB, EMB);
}

// Round 8
// 204.621 us; speedup vs baseline: 2.2265x; 1.0008x over previous
//
#include <hip/hip_runtime.h>
#include <stdint.h>

#define SEQ 2048
#define BSZ 4
#define NH 16
#define HD 64
#define EMB 1024
#define NT (SEQ / 64)
#define QSCALE 0.1803368801111f   // 0.125 * log2(e)

using bf16x8 = __attribute__((ext_vector_type(8))) __bf16;
using u16x8  = __attribute__((ext_vector_type(8))) unsigned short;
using u32x4  = __attribute__((ext_vector_type(4))) uint32_t;
using f32x4  = __attribute__((ext_vector_type(4))) float;
using f32x16 = __attribute__((ext_vector_type(16))) float;

__device__ __forceinline__ float exp2v(float x) { return __builtin_amdgcn_exp2f(x); }

__device__ __forceinline__ unsigned short f2bf(float f) {
    union { float f; uint32_t u; } v; v.f = f;
    uint32_t r = v.u + 0x7fffu + ((v.u >> 16) & 1u);
    return (unsigned short)(r >> 16);
}

__device__ __forceinline__ uint32_t cvtpk(float lo, float hi) {
    uint32_t r;
    asm("v_cvt_pk_bf16_f32 %0, %1, %2" : "=v"(r) : "v"(lo), "v"(hi));
    return r;
}
__device__ __forceinline__ void plswap(uint32_t& a, uint32_t& b) {
    asm volatile("v_permlane32_swap_b32 %0, %1" : "+v"(a), "+v"(b));
}

// async global->LDS, 16B per lane; dest = wave-uniform base + lane*16
__device__ __forceinline__ void gload16(void* lds, const void* g) {
    __builtin_amdgcn_global_load_lds(
        (const __attribute__((address_space(1))) void*)g,
        (__attribute__((address_space(3))) void*)lds, 16, 0, 0);
}

// ---------------- cast fp32 -> bf16 ----------------
__global__ void cast_kernel(const float* __restrict__ s, unsigned short* __restrict__ d, int n) {
    int i = (blockIdx.x * blockDim.x + threadIdx.x) * 4;
    if (i + 3 >= n) {
        for (int j = 0; j < 4 && i + j < n; ++j) d[i + j] = f2bf(s[i + j]);
        return;
    }
    float4 v = *(const float4*)(s + i);
    ushort4 o;
    o.x = f2bf(v.x); o.y = f2bf(v.y); o.z = f2bf(v.z); o.w = f2bf(v.w);
    *(ushort4*)(d + i) = o;
}

// ---------------- GEMM (m97 structure): C = A[M,K] * Bw[N,K]^T + bias ------
// MODE 0: f32 out to C0 (bias b0).  MODE 2: QKV fused — by 0-7 -> Q (scaled
// by QSCALE), 8-15 -> K, 16-23 -> V^T (transposed write [b,h,d,seq]).
template <int MODE>
__global__ __launch_bounds__(256, 2)
void gemm_bt(const unsigned short* __restrict__ A,
             const unsigned short* __restrict__ Bw,
             const float* __restrict__ b0, const float* __restrict__ b1,
             const float* __restrict__ b2,
             void* __restrict__ C0, void* __restrict__ C1, void* __restrict__ C2,
             int M, int N, int Kd) {
    __shared__ unsigned short As[128][64];
    __shared__ unsigned short Bs[128][64];

    const int t    = threadIdx.x;
    const int lane = t & 63;
    const int wid  = t >> 6;
    const int g    = lane >> 4;
    const int lr   = lane & 15;
    const int wm   = wid >> 1, wn = wid & 1;
    const int m0   = blockIdx.x * 128, n0 = blockIdx.y * 128;
    const int srow = lane >> 3;          // 0..7 within 8-row stripe
    const int scol = (lane & 7) * 8;     // shorts

    f32x4 acc[4][4];
    const f32x4 zero = {0.f, 0.f, 0.f, 0.f};
#pragma unroll
    for (int i = 0; i < 4; ++i)
#pragma unroll
        for (int j = 0; j < 4; ++j) acc[i][j] = zero;

    for (int kt = 0; kt < Kd; kt += 64) {
#pragma unroll
        for (int p = 0; p < 4; ++p) {
            int rowA = wid * 32 + p * 8;
            gload16(&As[rowA][0], A  + (size_t)(m0 + rowA + srow) * Kd + kt + scol);
            gload16(&Bs[rowA][0], Bw + (size_t)(n0 + rowA + srow) * Kd + kt + scol);
        }
        __syncthreads();   // compiler drains vmcnt before barrier
#pragma unroll
        for (int ks = 0; ks < 2; ++ks) {
            bf16x8 af[4], bfr[4];
#pragma unroll
            for (int m = 0; m < 4; ++m)
                af[m] = *(const bf16x8*)&As[wm * 64 + m * 16 + lr][ks * 32 + g * 8];
#pragma unroll
            for (int n = 0; n < 4; ++n)
                bfr[n] = *(const bf16x8*)&Bs[wn * 64 + n * 16 + lr][ks * 32 + g * 8];
#pragma unroll
            for (int m = 0; m < 4; ++m)
#pragma unroll
                for (int n = 0; n < 4; ++n)
                    acc[m][n] = __builtin_amdgcn_mfma_f32_16x16x32_bf16(af[m], bfr[n], acc[m][n], 0, 0, 0);
        }
        __syncthreads();
    }

    int seg = MODE == 2 ? (n0 >> 10) : 0;
    if (MODE == 2 && seg == 2) {
        // V^T write: [b*1024 + colL][seq], 4 consecutive seq per ushort4
        unsigned short* CwT = (unsigned short*)C2;
        int nl = n0 & 1023;
#pragma unroll
        for (int n = 0; n < 4; ++n) {
            int colL = nl + wn * 64 + n * 16 + lr;
            float bv = b2[colL];
#pragma unroll
            for (int m = 0; m < 4; ++m) {
                int rowg = m0 + wm * 64 + m * 16 + g * 4;
                int bb = rowg >> 11, seq = rowg & 2047;
                ushort4 w;
                w.x = f2bf(acc[m][n][0] + bv);
                w.y = f2bf(acc[m][n][1] + bv);
                w.z = f2bf(acc[m][n][2] + bv);
                w.w = f2bf(acc[m][n][3] + bv);
                *(ushort4*)(CwT + ((size_t)(bb * 1024 + colL)) * SEQ + seq) = w;
            }
        }
        return;
    }

    const float* bias;
    unsigned short* Cw = nullptr;
    float* Cf = nullptr;
    float scl = 1.0f;
    int nl;
    if (MODE == 2) {
        bias = seg == 0 ? b0 : b1;
        Cw = (unsigned short*)(seg == 0 ? C0 : C1);
        scl = seg == 0 ? QSCALE : 1.0f;
        nl = n0 & 1023;
    } else {
        bias = b0; Cf = (float*)C0; nl = n0;
    }
#pragma unroll
    for (int n = 0; n < 4; ++n) {
        int colL = nl + wn * 64 + n * 16 + lr;
        float bv = bias[colL];
#pragma unroll
        for (int m = 0; m < 4; ++m) {
            int rowg = m0 + wm * 64 + m * 16 + g * 4;
#pragma unroll
            for (int r = 0; r < 4; ++r) {
                float val = (acc[m][n][r] + bv) * scl;
                if (MODE == 2)
                    Cw[(size_t)(rowg + r) * EMB + colL] = f2bf(val);
                else
                    Cf[(size_t)(rowg + r) * EMB + colL] = val;
            }
        }
    }
}

// ---------------- Flash attention v7: MFMA row-sum, gload_lds staging ------
// Q pre-scaled by 0.125*log2e -> scores are base-2 logits. V comes in as V^T.
// grid: 512 blocks (XCD-swizzled); block 512 = 8 waves; wave = 32 q-rows.
__global__ __launch_bounds__(512, 4)
void flash_attn(const unsigned short* __restrict__ Q,
                const unsigned short* __restrict__ K,
                const unsigned short* __restrict__ VT,
                unsigned short* __restrict__ O) {
    __shared__ unsigned char KsB[2][64 * 128];   // K[k][d],  XOR-16B swizzled
    __shared__ unsigned char VtB[2][64 * 128];   // V^T[d][k], XOR-16B swizzled

    // bijective XCD swizzle: 512 blocks, 8 XCDs, 64 consecutive per XCD
    const int nwg  = gridDim.x * gridDim.y * gridDim.z;
    const int cpx  = nwg >> 3;
    const int bid0 = (blockIdx.z * gridDim.y + blockIdx.y) * gridDim.x + blockIdx.x;
    const int bid  = (bid0 % 8) * cpx + (bid0 / 8);
    const int bx   = bid & (gridDim.x - 1);          // SEQ/256 = 8 (pow2)
    const int h    = (bid >> 3) & 15;
    const int b    = bid >> 7;

    const int t    = threadIdx.x;
    const int wid  = t >> 6;
    const int lane = t & 63;
    const int l31  = lane & 31;
    const int hi   = lane >> 5;
    const int hi16 = hi << 4;
    const int sw   = (l31 & 7) << 4;
    const int qbase = bx * 256 + wid * 32;
    const size_t rowbase = (size_t)b * SEQ;
    const unsigned short* Kh  = K + rowbase * EMB + h * HD;
    const unsigned short* Vth = VT + (size_t)(b * 1024 + h * HD) * SEQ;

    // staging geometry: slot t stages 16B; LDS linear, source pre-swizzled
    const int grow = t >> 3;                         // K row / V^T d-row
    const int gc16 = (t & 7) ^ (grow & 7);           // XOR moved to source
    const unsigned short* Ksrc0 = Kh  + (size_t)grow * EMB + gc16 * 8;
    const unsigned short* Vsrc0 = Vth + (size_t)grow * SEQ + gc16 * 8;

    bf16x8 qf[4];
#pragma unroll
    for (int db = 0; db < 4; ++db)
        qf[db] = *(const bf16x8*)(Q + (rowbase + qbase + l31) * EMB + h * HD + db * 16 + hi * 8);

    // all-ones B fragment: P x ones-MFMA computes the softmax row-sum in
    // the SAME C-layout (and same rescale recurrence) as o0/o1.
    bf16x8 vones;
#pragma unroll
    for (int j = 0; j < 8; ++j) vones[j] = (__bf16)1.0f;

    f32x16 o0, o1, o2;
#pragma unroll
    for (int r = 0; r < 16; ++r) { o0[r] = 0.f; o1[r] = 0.f; o2[r] = 0.f; }
    float me = -1e30f;

    auto issue_tile = [&](int kt) {
        unsigned char* Ks = KsB[kt & 1] + wid * 1024;   // wave-uniform base
        unsigned char* Vt = VtB[kt & 1] + wid * 1024;
        gload16(Ks, Ksrc0 + (size_t)kt * 64 * EMB);     // K rows advance by kt*64
        gload16(Vt, Vsrc0 + kt * 64);                   // V^T cols advance by kt*64
    };
    issue_tile(0);

    for (int kt = 0; kt < NT; ++kt) {
        unsigned char* Ks = KsB[kt & 1];
        unsigned char* Vt = VtB[kt & 1];

        __syncthreads();                      // drains DMA for tile kt; prev reads done

        if (kt + 1 < NT) issue_tile(kt + 1);  // DMA next tile into other buffer

        // S^T = K * Q^T : lane holds 32 k-scores for q = lane&31 (base-2 logits)
        f32x16 s0, s1;
#pragma unroll
        for (int r = 0; r < 16; ++r) { s0[r] = 0.f; s1[r] = 0.f; }
        __builtin_amdgcn_s_setprio(1);
#pragma unroll
        for (int db = 0; db < 4; ++db) {
            bf16x8 kf0 = *(const bf16x8*)(Ks + l31 * 128        + ((db * 32 + hi16) ^ sw));
            bf16x8 kf1 = *(const bf16x8*)(Ks + (l31 + 32) * 128 + ((db * 32 + hi16) ^ sw));
            s0 = __builtin_amdgcn_mfma_f32_32x32x16_bf16(kf0, qf[db], s0, 0, 0, 0);
            s1 = __builtin_amdgcn_mfma_f32_32x32x16_bf16(kf1, qf[db], s1, 0, 0, 0);
        }
        __builtin_amdgcn_s_setprio(0);

        // row max (max3-friendly nesting)
        float pm = fmaxf(fmaxf(s0[0], s0[1]), s0[2]);
#pragma unroll
        for (int r = 3; r < 15; r += 2) pm = fmaxf(fmaxf(pm, s0[r]), s0[r + 1]);
        pm = fmaxf(pm, s0[15]);
#pragma unroll
        for (int r = 0; r < 16; r += 2) pm = fmaxf(fmaxf(pm, s1[r]), s1[r + 1]);
        pm = fmaxf(pm, __shfl_xor(pm, 32));

        // defer-max: only rescale when max grew by > 8 (P bounded by 2^8)
        if (!__all(pm - me <= 8.0f)) {
            float mn = fmaxf(me, pm);
            float al = exp2v(me - mn);
            me = mn;
#pragma unroll
            for (int r = 0; r < 16; ++r) {
                int addr = hi16 + (((r & 3) + 8 * (r >> 2)) << 2);
                float ar = __int_as_float(
                    __builtin_amdgcn_ds_bpermute(addr, __float_as_int(al)));
                o0[r] *= ar; o1[r] *= ar; o2[r] *= ar;
            }
        }

        // exp2 (packed subtract, then trans-pipe exp2; row-sum is MFMA'd below)
        s0 = s0 - me;
        s1 = s1 - me;
#pragma unroll
        for (int r = 0; r < 16; ++r) s0[r] = exp2v(s0[r]);
#pragma unroll
        for (int r = 0; r < 16; ++r) s1[r] = exp2v(s1[r]);

        // pack P -> bf16 A-fragments via cvt_pk + permlane32_swap
        bf16x8 pa[4];
#pragma unroll
        for (int kb = 0; kb < 2; ++kb) {
            uint32_t dw[8];
#pragma unroll
            for (int i = 0; i < 8; ++i)
                dw[i] = kb == 0 ? cvtpk(s0[2 * i], s0[2 * i + 1])
                                : cvtpk(s1[2 * i], s1[2 * i + 1]);
            plswap(dw[0], dw[2]); plswap(dw[1], dw[3]);
            plswap(dw[4], dw[6]); plswap(dw[5], dw[7]);
            u32x4 w0 = {dw[0], dw[1], dw[2], dw[3]};
            u32x4 w1 = {dw[4], dw[5], dw[6], dw[7]};
            pa[kb * 2]     = __builtin_bit_cast(bf16x8, w0);
            pa[kb * 2 + 1] = __builtin_bit_cast(bf16x8, w1);
        }

        // PV + row-sum (P x ones)
        __builtin_amdgcn_s_setprio(1);
#pragma unroll
        for (int kk = 0; kk < 4; ++kk) {
            bf16x8 vf0 = *(const bf16x8*)(Vt + l31 * 128        + ((kk * 32 + hi16) ^ sw));
            bf16x8 vf1 = *(const bf16x8*)(Vt + (l31 + 32) * 128 + ((kk * 32 + hi16) ^ sw));
            o0 = __builtin_amdgcn_mfma_f32_32x32x16_bf16(pa[kk], vf0, o0, 0, 0, 0);
            o1 = __builtin_amdgcn_mfma_f32_32x32x16_bf16(pa[kk], vf1, o1, 0, 0, 0);
            o2 = __builtin_amdgcn_mfma_f32_32x32x16_bf16(pa[kk], vones, o2, 0, 0, 0);
        }
        __builtin_amdgcn_s_setprio(0);
    }

    // epilogue: o2[r] holds the softmax denominator for this lane's q-row
#pragma unroll
    for (int r = 0; r < 16; ++r) {
        float inv = 1.0f / o2[r];
        int q = qbase + (r & 3) + 8 * (r >> 2) + 4 * hi;
        size_t ro = (rowbase + q) * EMB + h * HD;
        O[ro + l31]      = f2bf(o0[r] * inv);
        O[ro + 32 + l31] = f2bf(o1[r] * inv);
    }
}

extern "C" void kernel_launch(void* const* d_in, const int* in_sizes, int n_in,
                              void* d_out, int out_size, void* d_ws, size_t ws_size,
                              hipStream_t stream) {
    const float* x  = (const float*)d_in[0];
    const float* wq = (const float*)d_in[1];
    const float* bq = (const float*)d_in[2];
    const float* wk = (const float*)d_in[3];
    const float* bk = (const float*)d_in[4];
    const float* wv = (const float*)d_in[5];
    const float* bv = (const float*)d_in[6];
    const float* wo = (const float*)d_in[7];
    const float* bo = (const float*)d_in[8];

    char* ws = (char*)d_ws;
    const size_t M = (size_t)BSZ * SEQ;              // 8192
    unsigned short* xb    = (unsigned short*)ws;                       // 16 MB, reused as attn out
    unsigned short* wqkvb = (unsigned short*)(ws + (size_t)16 * 1024 * 1024);  // 6 MB
    unsigned short* wob   = (unsigned short*)(ws + (size_t)22 * 1024 * 1024);  // 2 MB
    unsigned short* Qb    = (unsigned short*)(ws + (size_t)24 * 1024 * 1024);
    unsigned short* Kb    = Qb + M * EMB;
    unsigned short* VTb   = Kb + M * EMB;            // V^T [b*16+h][64][2048]

    const int nX = (int)(M * EMB);
    cast_kernel<<<nX / 1024, 256, 0, stream>>>(x, xb, nX);
    cast_kernel<<<1024, 256, 0, stream>>>(wq, wqkvb,                 EMB * EMB);
    cast_kernel<<<1024, 256, 0, stream>>>(wk, wqkvb + 1024 * 1024,   EMB * EMB);
    cast_kernel<<<1024, 256, 0, stream>>>(wv, wqkvb + 2 * 1024 * 1024, EMB * EMB);
    cast_kernel<<<1024, 256, 0, stream>>>(wo, wob, EMB * EMB);

    gemm_bt<2><<<dim3(64, 24), 256, 0, stream>>>(xb, wqkvb, bq, bk, bv,
                                                 Qb, Kb, VTb, (int)M, 3 * EMB, EMB);

    flash_attn<<<dim3(SEQ / 256, NH, BSZ), 512, 0, stream>>>(Qb, Kb, VTb, xb);

    gemm_bt<0><<<dim3(64, 8), 256, 0, stream>>>(xb, wob, bo, nullptr, nullptr,
                                                d_out, nullptr, nullptr, (int)M, EMB, EMB);
}

// Round 10
// 203.638 us; speedup vs baseline: 2.2373x; 1.0048x over previous
//
#include <hip/hip_runtime.h>
#include <stdint.h>

#define SEQ 2048
#define BSZ 4
#define NH 16
#define HD 64
#define EMB 1024
#define NT (SEQ / 64)
#define QSCALE 0.1803368801111f   // 0.125 * log2(e)

using bf16x8 = __attribute__((ext_vector_type(8))) __bf16;
using u16x8  = __attribute__((ext_vector_type(8))) unsigned short;
using u32x4  = __attribute__((ext_vector_type(4))) uint32_t;
using f32x4  = __attribute__((ext_vector_type(4))) float;
using f32x16 = __attribute__((ext_vector_type(16))) float;

__device__ __forceinline__ float exp2v(float x) { return __builtin_amdgcn_exp2f(x); }

__device__ __forceinline__ unsigned short f2bf(float f) {
    union { float f; uint32_t u; } v; v.f = f;
    uint32_t r = v.u + 0x7fffu + ((v.u >> 16) & 1u);
    return (unsigned short)(r >> 16);
}

__device__ __forceinline__ uint32_t cvtpk(float lo, float hi) {
    uint32_t r;
    asm("v_cvt_pk_bf16_f32 %0, %1, %2" : "=v"(r) : "v"(lo), "v"(hi));
    return r;
}
__device__ __forceinline__ void plswap(uint32_t& a, uint32_t& b) {
    asm volatile("v_permlane32_swap_b32 %0, %1" : "+v"(a), "+v"(b));
}

// async global->LDS, 16B per lane; dest = wave-uniform base + lane*16
__device__ __forceinline__ void gload16(void* lds, const void* g) {
    __builtin_amdgcn_global_load_lds(
        (const __attribute__((address_space(1))) void*)g,
        (__attribute__((address_space(3))) void*)lds, 16, 0, 0);
}

// ---------------- cast fp32 -> bf16 ----------------
__global__ void cast_kernel(const float* __restrict__ s, unsigned short* __restrict__ d, int n) {
    int i = (blockIdx.x * blockDim.x + threadIdx.x) * 4;
    if (i + 3 >= n) {
        for (int j = 0; j < 4 && i + j < n; ++j) d[i + j] = f2bf(s[i + j]);
        return;
    }
    float4 v = *(const float4*)(s + i);
    ushort4 o;
    o.x = f2bf(v.x); o.y = f2bf(v.y); o.z = f2bf(v.z); o.w = f2bf(v.w);
    *(ushort4*)(d + i) = o;
}

// 4 weight matrices (1024x1024 each) in one launch; grid (1024, 4)
__global__ void cast4_kernel(const float* __restrict__ w0, const float* __restrict__ w1,
                             const float* __restrict__ w2, const float* __restrict__ w3,
                             unsigned short* __restrict__ d0, unsigned short* __restrict__ d1,
                             unsigned short* __restrict__ d2, unsigned short* __restrict__ d3) {
    const float* s; unsigned short* d;
    switch (blockIdx.y) {
        case 0:  s = w0; d = d0; break;
        case 1:  s = w1; d = d1; break;
        case 2:  s = w2; d = d2; break;
        default: s = w3; d = d3; break;
    }
    int i = (blockIdx.x * blockDim.x + threadIdx.x) * 4;
    float4 v = *(const float4*)(s + i);
    ushort4 o;
    o.x = f2bf(v.x); o.y = f2bf(v.y); o.z = f2bf(v.z); o.w = f2bf(v.w);
    *(ushort4*)(d + i) = o;
}

// ---------------- GEMM (m97 structure): C = A[M,K] * Bw[N,K]^T + bias ------
// MODE 0: f32 out to C0 (bias b0).  MODE 2: QKV fused — by 0-7 -> Q (scaled
// by QSCALE), 8-15 -> K, 16-23 -> V^T (transposed write [b,h,d,seq]).
template <int MODE>
__global__ __launch_bounds__(256, 2)
void gemm_bt(const unsigned short* __restrict__ A,
             const unsigned short* __restrict__ Bw,
             const float* __restrict__ b0, const float* __restrict__ b1,
             const float* __restrict__ b2,
             void* __restrict__ C0, void* __restrict__ C1, void* __restrict__ C2,
             int M, int N, int Kd) {
    __shared__ unsigned short As[128][64];
    __shared__ unsigned short Bs[128][64];

    const int t    = threadIdx.x;
    const int lane = t & 63;
    const int wid  = t >> 6;
    const int g    = lane >> 4;
    const int lr   = lane & 15;
    const int wm   = wid >> 1, wn = wid & 1;
    const int m0   = blockIdx.x * 128, n0 = blockIdx.y * 128;
    const int srow = lane >> 3;          // 0..7 within 8-row stripe
    const int scol = (lane & 7) * 8;     // shorts

    f32x4 acc[4][4];
    const f32x4 zero = {0.f, 0.f, 0.f, 0.f};
#pragma unroll
    for (int i = 0; i < 4; ++i)
#pragma unroll
        for (int j = 0; j < 4; ++j) acc[i][j] = zero;

    for (int kt = 0; kt < Kd; kt += 64) {
#pragma unroll
        for (int p = 0; p < 4; ++p) {
            int rowA = wid * 32 + p * 8;
            gload16(&As[rowA][0], A  + (size_t)(m0 + rowA + srow) * Kd + kt + scol);
            gload16(&Bs[rowA][0], Bw + (size_t)(n0 + rowA + srow) * Kd + kt + scol);
        }
        __syncthreads();   // compiler drains vmcnt before barrier
#pragma unroll
        for (int ks = 0; ks < 2; ++ks) {
            bf16x8 af[4], bfr[4];
#pragma unroll
            for (int m = 0; m < 4; ++m)
                af[m] = *(const bf16x8*)&As[wm * 64 + m * 16 + lr][ks * 32 + g * 8];
#pragma unroll
            for (int n = 0; n < 4; ++n)
                bfr[n] = *(const bf16x8*)&Bs[wn * 64 + n * 16 + lr][ks * 32 + g * 8];
#pragma unroll
            for (int m = 0; m < 4; ++m)
#pragma unroll
                for (int n = 0; n < 4; ++n)
                    acc[m][n] = __builtin_amdgcn_mfma_f32_16x16x32_bf16(af[m], bfr[n], acc[m][n], 0, 0, 0);
        }
        __syncthreads();
    }

    int seg = MODE == 2 ? (n0 >> 10) : 0;
    if (MODE == 2 && seg == 2) {
        // V^T write: [b*1024 + colL][seq], 4 consecutive seq per ushort4
        unsigned short* CwT = (unsigned short*)C2;
        int nl = n0 & 1023;
#pragma unroll
        for (int n = 0; n < 4; ++n) {
            int colL = nl + wn * 64 + n * 16 + lr;
            float bv = b2[colL];
#pragma unroll
            for (int m = 0; m < 4; ++m) {
                int rowg = m0 + wm * 64 + m * 16 + g * 4;
                int bb = rowg >> 11, seq = rowg & 2047;
                ushort4 w;
                w.x = f2bf(acc[m][n][0] + bv);
                w.y = f2bf(acc[m][n][1] + bv);
                w.z = f2bf(acc[m][n][2] + bv);
                w.w = f2bf(acc[m][n][3] + bv);
                *(ushort4*)(CwT + ((size_t)(bb * 1024 + colL)) * SEQ + seq) = w;
            }
        }
        return;
    }

    const float* bias;
    unsigned short* Cw = nullptr;
    float* Cf = nullptr;
    float scl = 1.0f;
    int nl;
    if (MODE == 2) {
        bias = seg == 0 ? b0 : b1;
        Cw = (unsigned short*)(seg == 0 ? C0 : C1);
        scl = seg == 0 ? QSCALE : 1.0f;
        nl = n0 & 1023;
    } else {
        bias = b0; Cf = (float*)C0; nl = n0;
    }
#pragma unroll
    for (int n = 0; n < 4; ++n) {
        int colL = nl + wn * 64 + n * 16 + lr;
        float bv = bias[colL];
#pragma unroll
        for (int m = 0; m < 4; ++m) {
            int rowg = m0 + wm * 64 + m * 16 + g * 4;
#pragma unroll
            for (int r = 0; r < 4; ++r) {
                float val = (acc[m][n][r] + bv) * scl;
                if (MODE == 2)
                    Cw[(size_t)(rowg + r) * EMB + colL] = f2bf(val);
                else
                    Cf[(size_t)(rowg + r) * EMB + colL] = val;
            }
        }
    }
}

// ---------------- Flash attention v9: 2-tile pipeline (PV(k-1) || QK(k)) ---
// Round-8 softmax (defer-max online, ones-MFMA denominator) + 3-buffer LDS
// so the PV of tile k-1 overlaps the QK of tile k (independent MFMA chains).
// grid: 512 blocks (XCD-swizzled); block 512 = 8 waves; wave = 32 q-rows.
__global__ __launch_bounds__(512, 4)
void flash_attn(const unsigned short* __restrict__ Q,
                const unsigned short* __restrict__ K,
                const unsigned short* __restrict__ VT,
                unsigned short* __restrict__ O) {
    __shared__ unsigned char KsB[3][64 * 128];   // K[k][d],  XOR-16B swizzled
    __shared__ unsigned char VtB[3][64 * 128];   // V^T[d][k], XOR-16B swizzled

    // bijective XCD swizzle: 512 blocks, 8 XCDs, 64 consecutive per XCD
    const int nwg  = gridDim.x * gridDim.y * gridDim.z;
    const int cpx  = nwg >> 3;
    const int bid0 = (blockIdx.z * gridDim.y + blockIdx.y) * gridDim.x + blockIdx.x;
    const int bid  = (bid0 % 8) * cpx + (bid0 / 8);
    const int bx   = bid & (gridDim.x - 1);          // SEQ/256 = 8 (pow2)
    const int h    = (bid >> 3) & 15;
    const int b    = bid >> 7;

    const int t    = threadIdx.x;
    const int wid  = t >> 6;
    const int lane = t & 63;
    const int l31  = lane & 31;
    const int hi   = lane >> 5;
    const int hi16 = hi << 4;
    const int sw   = (l31 & 7) << 4;
    const int qbase = bx * 256 + wid * 32;
    const size_t rowbase = (size_t)b * SEQ;
    const unsigned short* Kh  = K + rowbase * EMB + h * HD;
    const unsigned short* Vth = VT + (size_t)(b * 1024 + h * HD) * SEQ;

    // staging geometry: slot t stages 16B; LDS linear, source pre-swizzled
    const int grow = t >> 3;                         // K row / V^T d-row
    const int gc16 = (t & 7) ^ (grow & 7);           // XOR moved to source
    const unsigned short* Ksrc0 = Kh  + (size_t)grow * EMB + gc16 * 8;
    const unsigned short* Vsrc0 = Vth + (size_t)grow * SEQ + gc16 * 8;

    bf16x8 qf[4];
#pragma unroll
    for (int db = 0; db < 4; ++db)
        qf[db] = *(const bf16x8*)(Q + (rowbase + qbase + l31) * EMB + h * HD + db * 16 + hi * 8);

    // all-ones B fragment: P x ones MFMA = softmax denominator in C-layout
    bf16x8 vones;
#pragma unroll
    for (int j = 0; j < 8; ++j) vones[j] = (__bf16)1.0f;

    f32x16 o0, o1, o2;
#pragma unroll
    for (int r = 0; r < 16; ++r) { o0[r] = 0.f; o1[r] = 0.f; o2[r] = 0.f; }
    float me = -1e30f;

    auto issue_tile = [&](int kt, int buf) {
        gload16(KsB[buf] + wid * 1024, Ksrc0 + (size_t)kt * 64 * EMB);
        gload16(VtB[buf] + wid * 1024, Vsrc0 + kt * 64);
    };

    auto qk = [&](const unsigned char* Ks, f32x16& s0, f32x16& s1) {
#pragma unroll
        for (int r = 0; r < 16; ++r) { s0[r] = 0.f; s1[r] = 0.f; }
        __builtin_amdgcn_s_setprio(1);
#pragma unroll
        for (int db = 0; db < 4; ++db) {
            bf16x8 kf0 = *(const bf16x8*)(Ks + l31 * 128        + ((db * 32 + hi16) ^ sw));
            bf16x8 kf1 = *(const bf16x8*)(Ks + (l31 + 32) * 128 + ((db * 32 + hi16) ^ sw));
            s0 = __builtin_amdgcn_mfma_f32_32x32x16_bf16(kf0, qf[db], s0, 0, 0, 0);
            s1 = __builtin_amdgcn_mfma_f32_32x32x16_bf16(kf1, qf[db], s1, 0, 0, 0);
        }
        __builtin_amdgcn_s_setprio(0);
    };

    auto pv = [&](const unsigned char* Vt, const bf16x8* pa) {
        __builtin_amdgcn_s_setprio(1);
#pragma unroll
        for (int kk = 0; kk < 4; ++kk) {
            bf16x8 vf0 = *(const bf16x8*)(Vt + l31 * 128        + ((kk * 32 + hi16) ^ sw));
            bf16x8 vf1 = *(const bf16x8*)(Vt + (l31 + 32) * 128 + ((kk * 32 + hi16) ^ sw));
            o0 = __builtin_amdgcn_mfma_f32_32x32x16_bf16(pa[kk], vf0, o0, 0, 0, 0);
            o1 = __builtin_amdgcn_mfma_f32_32x32x16_bf16(pa[kk], vf1, o1, 0, 0, 0);
            o2 = __builtin_amdgcn_mfma_f32_32x32x16_bf16(pa[kk], vones, o2, 0, 0, 0);
        }
        __builtin_amdgcn_s_setprio(0);
    };

    auto softmax_pack = [&](f32x16& s0, f32x16& s1, bf16x8* pa, bool first) {
        // row max (this lane holds 32 of 64 k-scores; partner half has rest)
        float pm = fmaxf(fmaxf(s0[0], s0[1]), s0[2]);
#pragma unroll
        for (int r = 3; r < 15; r += 2) pm = fmaxf(fmaxf(pm, s0[r]), s0[r + 1]);
        pm = fmaxf(pm, s0[15]);
#pragma unroll
        for (int r = 0; r < 16; r += 2) pm = fmaxf(fmaxf(pm, s1[r]), s1[r + 1]);
        pm = fmaxf(pm, __shfl_xor(pm, 32));

        if (first) {
            me = pm;
        } else if (!__all(pm - me <= 8.0f)) {   // defer-max, THR=8
            float mn = fmaxf(me, pm);
            float al = exp2v(me - mn);
            me = mn;
#pragma unroll
            for (int r = 0; r < 16; ++r) {
                int addr = hi16 + (((r & 3) + 8 * (r >> 2)) << 2);
                float ar = __int_as_float(
                    __builtin_amdgcn_ds_bpermute(addr, __float_as_int(al)));
                o0[r] *= ar; o1[r] *= ar; o2[r] *= ar;
            }
        }

        s0 = s0 - me;
        s1 = s1 - me;
#pragma unroll
        for (int r = 0; r < 16; ++r) s0[r] = exp2v(s0[r]);
#pragma unroll
        for (int r = 0; r < 16; ++r) s1[r] = exp2v(s1[r]);

        // pack P -> bf16 A-fragments via cvt_pk + permlane32_swap
#pragma unroll
        for (int kb = 0; kb < 2; ++kb) {
            uint32_t dw[8];
#pragma unroll
            for (int i = 0; i < 8; ++i)
                dw[i] = kb == 0 ? cvtpk(s0[2 * i], s0[2 * i + 1])
                                : cvtpk(s1[2 * i], s1[2 * i + 1]);
            plswap(dw[0], dw[2]); plswap(dw[1], dw[3]);
            plswap(dw[4], dw[6]); plswap(dw[5], dw[7]);
            u32x4 w0 = {dw[0], dw[1], dw[2], dw[3]};
            u32x4 w1 = {dw[4], dw[5], dw[6], dw[7]};
            pa[kb * 2]     = __builtin_bit_cast(bf16x8, w0);
            pa[kb * 2 + 1] = __builtin_bit_cast(bf16x8, w1);
        }
    };

    // ---- prologue: tile 0 ----
    issue_tile(0, 0);
    __syncthreads();                 // DMA(0) drained
    issue_tile(1, 1);
    bf16x8 paA[4];
    {
        f32x16 s0, s1;
        qk(KsB[0], s0, s1);
        softmax_pack(s0, s1, paA, true);
    }

    // ---- pipelined main loop: QK(kt) || PV(kt-1) ----
    int prv = 0, cur = 1, nxt = 2;
    for (int kt = 1; kt < NT; ++kt) {
        __syncthreads();             // DMA(kt) drained; all reads of buf nxt done
        if (kt + 1 < NT) issue_tile(kt + 1, nxt);
        f32x16 s0, s1;
        qk(KsB[cur], s0, s1);        // independent of...
        pv(VtB[prv], paA);           // ...this: back-to-back MFMA streams
        softmax_pack(s0, s1, paA, false);
        int tmp = prv; prv = cur; cur = nxt; nxt = tmp;
    }
    pv(VtB[prv], paA);               // drain: PV of the last tile

    // epilogue: o2[r] holds the softmax denominator for this lane's q-row
#pragma unroll
    for (int r = 0; r < 16; ++r) {
        float inv = 1.0f / o2[r];
        int q = qbase + (r & 3) + 8 * (r >> 2) + 4 * hi;
        size_t ro = (rowbase + q) * EMB + h * HD;
        O[ro + l31]      = f2bf(o0[r] * inv);
        O[ro + 32 + l31] = f2bf(o1[r] * inv);
    }
}

extern "C" void kernel_launch(void* const* d_in, const int* in_sizes, int n_in,
                              void* d_out, int out_size, void* d_ws, size_t ws_size,
                              hipStream_t stream) {
    const float* x  = (const float*)d_in[0];
    const float* wq = (const float*)d_in[1];
    const float* bq = (const float*)d_in[2];
    const float* wk = (const float*)d_in[3];
    const float* bk = (const float*)d_in[4];
    const float* wv = (const float*)d_in[5];
    const float* bv = (const float*)d_in[6];
    const float* wo = (const float*)d_in[7];
    const float* bo = (const float*)d_in[8];

    char* ws = (char*)d_ws;
    const size_t M = (size_t)BSZ * SEQ;              // 8192
    unsigned short* xb    = (unsigned short*)ws;                       // 16 MB, reused as attn out
    unsigned short* wqkvb = (unsigned short*)(ws + (size_t)16 * 1024 * 1024);  // 6 MB
    unsigned short* wob   = (unsigned short*)(ws + (size_t)22 * 1024 * 1024);  // 2 MB
    unsigned short* Qb    = (unsigned short*)(ws + (size_t)24 * 1024 * 1024);
    unsigned short* Kb    = Qb + M * EMB;
    unsigned short* VTb   = Kb + M * EMB;            // V^T [b*16+h][64][2048]

    const int nX = (int)(M * EMB);
    cast_kernel<<<nX / 1024, 256, 0, stream>>>(x, xb, nX);
    cast4_kernel<<<dim3(1024, 4), 256, 0, stream>>>(
        wq, wk, wv, wo,
        wqkvb, wqkvb + 1024 * 1024, wqkvb + 2 * 1024 * 1024, wob);

    gemm_bt<2><<<dim3(64, 24), 256, 0, stream>>>(xb, wqkvb, bq, bk, bv,
                                                 Qb, Kb, VTb, (int)M, 3 * EMB, EMB);

    flash_attn<<<dim3(SEQ / 256, NH, BSZ), 512, 0, stream>>>(Qb, Kb, VTb, xb);

    gemm_bt<0><<<dim3(64, 8), 256, 0, stream>>>(xb, wob, bo, nullptr, nullptr,
                                                d_out, nullptr, nullptr, (int)M, EMB, EMB);
}